// Round 7
// baseline (1003.988 us; speedup 1.0000x reference)
//
#include <hip/hip_runtime.h>
#include <hip/hip_fp16.h>

constexpr int kN  = 50000;
constexpr int kE  = 400000;
constexpr int kHC = 128;
constexpr int kED = 32;
constexpr int kL  = 2;
#define EPS_LN 1e-5f
#define NEG_SLOPE 0.01f
#define RSQRT_C 0.17677669529663687f  // 1/sqrt(32)

// ---------------- Projection GEMM, fp16 q/k/v outputs + fp32 xr -------------
__global__ __launch_bounds__(256) void proj_kernel_h(
    const float* __restrict__ hin,
    const float* __restrict__ Wq, const float* __restrict__ bq,
    const float* __restrict__ Wk, const float* __restrict__ bk,
    const float* __restrict__ Wv, const float* __restrict__ bv,
    const float* __restrict__ Ws, const float* __restrict__ bs,
    __half* __restrict__ q, __half* __restrict__ k,
    __half* __restrict__ v, float* __restrict__ xr)
{
    __shared__ float xs[16 * kHC];
    const int t = threadIdx.x;
    const int row0 = blockIdx.x * 16;
    const float4* s4 = (const float4*)(hin + (size_t)row0 * kHC);
    float4* d4 = (float4*)xs;
    d4[t] = s4[t];
    d4[t + 256] = s4[t + 256];
    __syncthreads();

    const int c = t & 127;
    const int half = t >> 7;
    float acc0[8], acc1[8], acc2[8], acc3[8];
#pragma unroll
    for (int r = 0; r < 8; r++) { acc0[r] = 0.f; acc1[r] = 0.f; acc2[r] = 0.f; acc3[r] = 0.f; }
    const float* xbase = xs + (half * 8) * kHC;

    for (int k4 = 0; k4 < kHC; k4 += 4) {
        float4 xv[8];
#pragma unroll
        for (int r = 0; r < 8; r++) xv[r] = *(const float4*)(xbase + r * kHC + k4);
#pragma unroll
        for (int i = 0; i < 4; i++) {
            const int ki = k4 + i;
            const float wq = Wq[ki * kHC + c];
            const float wk = Wk[ki * kHC + c];
            const float wv = Wv[ki * kHC + c];
            const float wsv = Ws[ki * kHC + c];
#pragma unroll
            for (int r = 0; r < 8; r++) {
                const float xvi = ((const float*)&xv[r])[i];
                acc0[r] = fmaf(xvi, wq, acc0[r]);
                acc1[r] = fmaf(xvi, wk, acc1[r]);
                acc2[r] = fmaf(xvi, wv, acc2[r]);
                acc3[r] = fmaf(xvi, wsv, acc3[r]);
            }
        }
    }
    const float bqv = bq[c], bkv = bk[c], bvv = bv[c], bsv = bs[c];
#pragma unroll
    for (int r = 0; r < 8; r++) {
        const size_t o = (size_t)(row0 + half * 8 + r) * kHC + c;
        q[o]  = __float2half(acc0[r] + bqv);
        k[o]  = __float2half(acc1[r] + bkv);
        v[o]  = __float2half(acc2[r] + bvv);
        xr[o] = acc3[r] + bsv;
    }
}

// ---------------- fp32-output projection (fallback tier) --------------------
__global__ __launch_bounds__(256) void proj_kernel(
    const float* __restrict__ hin,
    const float* __restrict__ Wq, const float* __restrict__ bq,
    const float* __restrict__ Wk, const float* __restrict__ bk,
    const float* __restrict__ Wv, const float* __restrict__ bv,
    const float* __restrict__ Ws, const float* __restrict__ bs,
    float* __restrict__ q, float* __restrict__ k,
    float* __restrict__ v, float* __restrict__ xr)
{
    __shared__ float xs[16 * kHC];
    const int t = threadIdx.x;
    const int row0 = blockIdx.x * 16;
    const float4* s4 = (const float4*)(hin + (size_t)row0 * kHC);
    float4* d4 = (float4*)xs;
    d4[t] = s4[t];
    d4[t + 256] = s4[t + 256];
    __syncthreads();

    const int c = t & 127;
    const int half = t >> 7;
    float acc0[8], acc1[8], acc2[8], acc3[8];
#pragma unroll
    for (int r = 0; r < 8; r++) { acc0[r] = 0.f; acc1[r] = 0.f; acc2[r] = 0.f; acc3[r] = 0.f; }
    const float* xbase = xs + (half * 8) * kHC;

    for (int k4 = 0; k4 < kHC; k4 += 4) {
        float4 xv[8];
#pragma unroll
        for (int r = 0; r < 8; r++) xv[r] = *(const float4*)(xbase + r * kHC + k4);
#pragma unroll
        for (int i = 0; i < 4; i++) {
            const int ki = k4 + i;
            const float wq = Wq[ki * kHC + c];
            const float wk = Wk[ki * kHC + c];
            const float wv = Wv[ki * kHC + c];
            const float wsv = Ws[ki * kHC + c];
#pragma unroll
            for (int r = 0; r < 8; r++) {
                const float xvi = ((const float*)&xv[r])[i];
                acc0[r] = fmaf(xvi, wq, acc0[r]);
                acc1[r] = fmaf(xvi, wk, acc1[r]);
                acc2[r] = fmaf(xvi, wv, acc2[r]);
                acc3[r] = fmaf(xvi, wsv, acc3[r]);
            }
        }
    }
    const float bqv = bq[c], bkv = bk[c], bvv = bv[c], bsv = bs[c];
#pragma unroll
    for (int r = 0; r < 8; r++) {
        const size_t o = (size_t)(row0 + half * 8 + r) * kHC + c;
        q[o]  = acc0[r] + bqv;
        k[o]  = acc1[r] + bkv;
        v[o]  = acc2[r] + bvv;
        xr[o] = acc3[r] + bsv;
    }
}

// ---------------- CSR build (once per call) ---------------------------------
__global__ __launch_bounds__(256) void hist_kernel(
    const int* __restrict__ dstI, int* __restrict__ deg)
{
    const int e = blockIdx.x * 256 + threadIdx.x;
    if (e < kE) atomicAdd(&deg[dstI[e]], 1);
}

__global__ __launch_bounds__(1024) void scan_kernel(
    const int* __restrict__ deg, int* __restrict__ rowptr, int* __restrict__ cursor)
{
    const int t = threadIdx.x;
    constexpr int CH = (kN + 1023) / 1024;
    const int base = t * CH;
    const int end = base + CH < kN ? base + CH : kN;
    int lsum = 0;
    for (int i = base; i < end; i++) lsum += deg[i];
    __shared__ int sm[1024];
    sm[t] = lsum;
    __syncthreads();
    for (int off = 1; off < 1024; off <<= 1) {
        const int x = (t >= off) ? sm[t - off] : 0;
        __syncthreads();
        sm[t] += x;
        __syncthreads();
    }
    int running = sm[t] - lsum;
    for (int i = base; i < end; i++) {
        rowptr[i] = running;
        cursor[i] = running;
        running += deg[i];
    }
    if (t == 1023) rowptr[kN] = sm[1023];
}

__global__ __launch_bounds__(256) void scatter_kernel(
    const int* __restrict__ srcI, const int* __restrict__ dstI,
    int* __restrict__ cursor, int* __restrict__ esrc, int* __restrict__ eidx,
    int* __restrict__ edst)
{
    const int e = blockIdx.x * 256 + threadIdx.x;
    if (e >= kE) return;
    const int d = dstI[e];
    const int pos = atomicAdd(&cursor[d], 1);
    esrc[pos] = srcI[e];
    eidx[pos] = e;
    edst[pos] = d;
}

// ---------------- Edge precompute: aex + ve streams in CSR order ------------
constexpr int kPreWaves = 16384;  // 4096 blocks x 4 waves
__global__ __launch_bounds__(256) void edge_pre2_kernel(
    const __half* __restrict__ q16, const __half* __restrict__ k16,
    const __half* __restrict__ v16, const float* __restrict__ ea,
    const float* __restrict__ We, const float* __restrict__ be,
    const int* __restrict__ esrc, const int* __restrict__ eidx,
    const int* __restrict__ edst,
    float* __restrict__ aex, __half* __restrict__ ve)
{
    const int t = threadIdx.x;
    const int wid = blockIdx.x * 4 + (t >> 6);
    const int lane = t & 63;
    const int c = lane << 1;

    float we0[kED], we1[kED];
#pragma unroll
    for (int j = 0; j < kED; j++) {
        const float2 w = *(const float2*)&We[j * kHC + c];
        we0[j] = w.x; we1[j] = w.y;
    }
    const float be0 = be[c], be1 = be[c + 1];

    constexpr int CH = (kE + kPreWaves - 1) / kPreWaves;  // 25
    const int j0 = wid * CH;
    const int j1 = (j0 + CH < kE) ? j0 + CH : kE;
    for (int jj = j0; jj < j1; jj++) {
        const int s   = esrc[jj];
        const int eid = eidx[jj];
        const int d   = edst[jj];
        const float a = ea[(size_t)eid * kED + (lane & 31)];
        float e0 = be0, e1 = be1;
#pragma unroll
        for (int j = 0; j < kED; j++) {
            const float aj = __shfl(a, j, 32);
            e0 = fmaf(aj, we0[j], e0);
            e1 = fmaf(aj, we1[j], e1);
        }
        const float2 qf = __half22float2(*(const __half2*)&q16[(size_t)d * kHC + c]);
        const float2 kf = __half22float2(*(const __half2*)&k16[(size_t)s * kHC + c]);
        const float2 vf = __half22float2(*(const __half2*)&v16[(size_t)s * kHC + c]);
        float p = qf.x * (kf.x + e0) + qf.y * (kf.y + e1);
        p += __shfl_xor(p, 1);
        p += __shfl_xor(p, 2);
        p += __shfl_xor(p, 4);
        p += __shfl_xor(p, 8);
        if ((lane & 15) == 0) aex[(size_t)jj * 4 + (lane >> 4)] = __expf(p * RSQRT_C);
        *(__half2*)&ve[(size_t)jj * kHC + c] = __floats2half2_rn(vf.x + e0, vf.y + e1);
    }
}

// ---------------- Fused node pass: sequential streams + epilogue ------------
__global__ __launch_bounds__(256) void fused_stream_kernel(
    const float* __restrict__ aex, const __half* __restrict__ ve,
    const int* __restrict__ rowptr,
    const float* __restrict__ xr, const float* __restrict__ Wb,
    const float* __restrict__ lnw, const float* __restrict__ lnb,
    float* __restrict__ hout)
{
    const int t = threadIdx.x;
    const int n = blockIdx.x * 4 + (t >> 6);
    if (n >= kN) return;
    const int lane = t & 63;
    const int c = lane << 1;
    const int h = lane >> 4;

    float acc0 = 0.f, acc1 = 0.f, den = 0.f;
    const int beg = rowptr[n], endp = rowptr[n + 1];
    const __half2* ve2 = (const __half2*)ve;
    for (int jj = beg; jj < endp; jj++) {
        const float aexv = aex[(size_t)jj * 4 + h];
        const float2 vf = __half22float2(ve2[(size_t)jj * 64 + lane]);
        den += aexv;
        acc0 = fmaf(vf.x, aexv, acc0);
        acc1 = fmaf(vf.y, aexv, acc1);
    }
    const float invd = 1.f / (den + 1e-16f);
    const float o0 = acc0 * invd, o1 = acc1 * invd;

    const float2 r = *(const float2*)&xr[(size_t)n * kHC + c];
    float z = o0 * Wb[c] + o1 * Wb[c + 1]
            + r.x * Wb[kHC + c] + r.y * Wb[kHC + c + 1]
            + (o0 - r.x) * Wb[2 * kHC + c] + (o1 - r.y) * Wb[2 * kHC + c + 1];
#pragma unroll
    for (int m = 1; m < 64; m <<= 1) z += __shfl_xor(z, m);
    const float beta = 1.f / (1.f + __expf(-z));

    const float g0 = beta * r.x + (1.f - beta) * o0;
    const float g1 = beta * r.y + (1.f - beta) * o1;

    float sm = g0 + g1;
    float sq = g0 * g0 + g1 * g1;
#pragma unroll
    for (int m = 1; m < 64; m <<= 1) {
        sm += __shfl_xor(sm, m);
        sq += __shfl_xor(sq, m);
    }
    const float mu  = sm * (1.f / kHC);
    const float var = sq * (1.f / kHC) - mu * mu;
    const float inv = rsqrtf(var + EPS_LN);

    float y0 = (g0 - mu) * inv * lnw[c] + lnb[c];
    float y1 = (g1 - mu) * inv * lnw[c + 1] + lnb[c + 1];
    y0 = y0 > 0.f ? y0 : NEG_SLOPE * y0;
    y1 = y1 > 0.f ? y1 : NEG_SLOPE * y1;
    *(float2*)&hout[(size_t)n * kHC + c] = make_float2(y0, y1);
}

// ---------------- Fallback fused (gather path, 106 MB tier) -----------------
__global__ __launch_bounds__(256) void fused_kernel_fb(
    const float* __restrict__ q, const float* __restrict__ kk,
    const float* __restrict__ vv, const float* __restrict__ ea,
    const float* __restrict__ We, const float* __restrict__ be,
    const int* __restrict__ rowptr, const int* __restrict__ esrc,
    const int* __restrict__ eidx,
    const float* __restrict__ xr, const float* __restrict__ Wb,
    const float* __restrict__ lnw, const float* __restrict__ lnb,
    float* __restrict__ hout)
{
    const int t = threadIdx.x;
    const int n = blockIdx.x * 4 + (t >> 6);
    if (n >= kN) return;
    const int lane = t & 63;
    const int c = lane << 1;

    float we0[kED], we1[kED];
#pragma unroll
    for (int j = 0; j < kED; j++) {
        const float2 w = *(const float2*)&We[j * kHC + c];
        we0[j] = w.x; we1[j] = w.y;
    }
    const float be0 = be[c], be1 = be[c + 1];
    const float2 qv = *(const float2*)&q[(size_t)n * kHC + c];

    float acc0 = 0.f, acc1 = 0.f, den = 0.f;
    const int beg = rowptr[n], endp = rowptr[n + 1];
    for (int jj = beg; jj < endp; jj++) {
        const int s   = esrc[jj];
        const int eid = eidx[jj];
        const float a = ea[(size_t)eid * kED + (lane & 31)];
        float e0 = be0, e1 = be1;
#pragma unroll
        for (int j = 0; j < kED; j++) {
            const float aj = __shfl(a, j, 32);
            e0 = fmaf(aj, we0[j], e0);
            e1 = fmaf(aj, we1[j], e1);
        }
        const float2 kvv = *(const float2*)&kk[(size_t)s * kHC + c];
        const float2 vl = *(const float2*)&vv[(size_t)s * kHC + c];
        float p = qv.x * (kvv.x + e0) + qv.y * (kvv.y + e1);
        p += __shfl_xor(p, 1);
        p += __shfl_xor(p, 2);
        p += __shfl_xor(p, 4);
        p += __shfl_xor(p, 8);
        const float aexv = __expf(p * RSQRT_C);
        den += aexv;
        acc0 = fmaf(vl.x + e0, aexv, acc0);
        acc1 = fmaf(vl.y + e1, aexv, acc1);
    }
    const float invd = 1.f / (den + 1e-16f);
    const float o0 = acc0 * invd, o1 = acc1 * invd;

    const float2 r = *(const float2*)&xr[(size_t)n * kHC + c];
    float z = o0 * Wb[c] + o1 * Wb[c + 1]
            + r.x * Wb[kHC + c] + r.y * Wb[kHC + c + 1]
            + (o0 - r.x) * Wb[2 * kHC + c] + (o1 - r.y) * Wb[2 * kHC + c + 1];
#pragma unroll
    for (int m = 1; m < 64; m <<= 1) z += __shfl_xor(z, m);
    const float beta = 1.f / (1.f + __expf(-z));

    const float g0 = beta * r.x + (1.f - beta) * o0;
    const float g1 = beta * r.y + (1.f - beta) * o1;

    float sm = g0 + g1;
    float sq = g0 * g0 + g1 * g1;
#pragma unroll
    for (int m = 1; m < 64; m <<= 1) {
        sm += __shfl_xor(sm, m);
        sq += __shfl_xor(sq, m);
    }
    const float mu  = sm * (1.f / kHC);
    const float var = sq * (1.f / kHC) - mu * mu;
    const float inv = rsqrtf(var + EPS_LN);

    float y0 = (g0 - mu) * inv * lnw[c] + lnb[c];
    float y1 = (g1 - mu) * inv * lnw[c + 1] + lnb[c + 1];
    y0 = y0 > 0.f ? y0 : NEG_SLOPE * y0;
    y1 = y1 > 0.f ? y1 : NEG_SLOPE * y1;
    *(float2*)&hout[(size_t)n * kHC + c] = make_float2(y0, y1);
}

extern "C" void kernel_launch(void* const* d_in, const int* in_sizes, int n_in,
                              void* d_out, int out_size, void* d_ws, size_t ws_size,
                              hipStream_t stream)
{
    const float* x   = (const float*)d_in[0];
    const int*   ei  = (const int*)d_in[1];
    const float* ea  = (const float*)d_in[2];
    const float* Wq  = (const float*)d_in[3];
    const float* bq  = (const float*)d_in[4];
    const float* Wk  = (const float*)d_in[5];
    const float* bk  = (const float*)d_in[6];
    const float* Wv  = (const float*)d_in[7];
    const float* bv  = (const float*)d_in[8];
    const float* We  = (const float*)d_in[9];
    const float* be  = (const float*)d_in[10];
    const float* Wsk = (const float*)d_in[11];
    const float* bsk = (const float*)d_in[12];
    const float* Wb  = (const float*)d_in[13];
    const float* lnw = (const float*)d_in[14];
    const float* lnb = (const float*)d_in[15];
    float* out = (float*)d_out;

    const int* srcI = ei;
    const int* dstI = ei + kE;

    // ---- Tier-1 layout (~178 MB): fp16 q/k/v + fp32 xr + CSR + aex + ve ----
    __half* q16 = (__half*)d_ws;
    __half* k16 = q16 + (size_t)kN * kHC;
    __half* v16 = k16 + (size_t)kN * kHC;
    float*  xr1 = (float*)(v16 + (size_t)kN * kHC);
    int* deg1    = (int*)(xr1 + (size_t)kN * kHC);
    int* rowptr1 = deg1 + kN;
    int* cursor1 = rowptr1 + kN + 1;
    int* esrc1   = cursor1 + kN;
    int* eidx1   = esrc1 + kE;
    int* edst1   = eidx1 + kE;
    float* aex   = (float*)(edst1 + kE);
    __half* ve   = (__half*)(aex + (size_t)kE * 4);
    const size_t need1 = (size_t)((char*)(ve + (size_t)kE * kHC) - (char*)d_ws);

    if (ws_size >= need1) {
        hipMemsetAsync(deg1, 0, (size_t)kN * sizeof(int), stream);
        hist_kernel<<<(kE + 255) / 256, 256, 0, stream>>>(dstI, deg1);
        scan_kernel<<<1, 1024, 0, stream>>>(deg1, rowptr1, cursor1);
        scatter_kernel<<<(kE + 255) / 256, 256, 0, stream>>>(srcI, dstI, cursor1,
                                                             esrc1, eidx1, edst1);
        const float* hin = x;
        for (int l = 0; l < kL; l++) {
            proj_kernel_h<<<kN / 16, 256, 0, stream>>>(
                hin,
                Wq + (size_t)l * kHC * kHC, bq + (size_t)l * kHC,
                Wk + (size_t)l * kHC * kHC, bk + (size_t)l * kHC,
                Wv + (size_t)l * kHC * kHC, bv + (size_t)l * kHC,
                Wsk + (size_t)l * kHC * kHC, bsk + (size_t)l * kHC,
                q16, k16, v16, xr1);
            edge_pre2_kernel<<<kPreWaves / 4, 256, 0, stream>>>(
                q16, k16, v16, ea,
                We + (size_t)l * kED * kHC, be + (size_t)l * kHC,
                esrc1, eidx1, edst1, aex, ve);
            fused_stream_kernel<<<(kN + 3) / 4, 256, 0, stream>>>(
                aex, ve, rowptr1,
                xr1, Wb + (size_t)l * 3 * kHC,
                lnw + (size_t)l * kHC, lnb + (size_t)l * kHC,
                out);
            hin = out;
        }
        return;
    }

    // ---- Fallback tier (~106 MB): fp32 gather path --------------------------
    float* ws = (float*)d_ws;
    float* q  = ws;
    float* k  = q  + (size_t)kN * kHC;
    float* v  = k  + (size_t)kN * kHC;
    float* xr = v  + (size_t)kN * kHC;
    int* deg    = (int*)(xr + (size_t)kN * kHC);
    int* rowptr = deg + kN;
    int* cursor = rowptr + kN + 1;
    int* esrc   = cursor + kN;
    int* eidx   = esrc + kE;
    int* edst   = eidx + kE;

    hipMemsetAsync(deg, 0, (size_t)kN * sizeof(int), stream);
    hist_kernel<<<(kE + 255) / 256, 256, 0, stream>>>(dstI, deg);
    scan_kernel<<<1, 1024, 0, stream>>>(deg, rowptr, cursor);
    scatter_kernel<<<(kE + 255) / 256, 256, 0, stream>>>(srcI, dstI, cursor,
                                                         esrc, eidx, edst);
    const float* hin = x;
    for (int l = 0; l < kL; l++) {
        proj_kernel<<<kN / 16, 256, 0, stream>>>(
            hin,
            Wq + (size_t)l * kHC * kHC, bq + (size_t)l * kHC,
            Wk + (size_t)l * kHC * kHC, bk + (size_t)l * kHC,
            Wv + (size_t)l * kHC * kHC, bv + (size_t)l * kHC,
            Wsk + (size_t)l * kHC * kHC, bsk + (size_t)l * kHC,
            q, k, v, xr);
        fused_kernel_fb<<<(kN + 3) / 4, 256, 0, stream>>>(
            q, k, v, ea,
            We + (size_t)l * kED * kHC, be + (size_t)l * kHC,
            rowptr, esrc, eidx,
            xr, Wb + (size_t)l * 3 * kHC,
            lnw + (size_t)l * kHC, lnb + (size_t)l * kHC,
            out);
        hin = out;
    }
}

// Round 8
// 849.814 us; speedup vs baseline: 1.1814x; 1.1814x over previous
//
#include <hip/hip_runtime.h>
#include <hip/hip_fp16.h>

constexpr int kN  = 50000;
constexpr int kE  = 400000;
constexpr int kHC = 128;
constexpr int kED = 32;
constexpr int kL  = 2;
#define EPS_LN 1e-5f
#define NEG_SLOPE 0.01f
#define RSQRT_C 0.17677669529663687f  // 1/sqrt(32)

// ---------------- Projection GEMM, fp16 q/k/v outputs + fp32 xr -------------
__global__ __launch_bounds__(256) void proj_kernel_h(
    const float* __restrict__ hin,
    const float* __restrict__ Wq, const float* __restrict__ bq,
    const float* __restrict__ Wk, const float* __restrict__ bk,
    const float* __restrict__ Wv, const float* __restrict__ bv,
    const float* __restrict__ Ws, const float* __restrict__ bs,
    __half* __restrict__ q, __half* __restrict__ k,
    __half* __restrict__ v, float* __restrict__ xr)
{
    __shared__ float xs[16 * kHC];
    const int t = threadIdx.x;
    const int row0 = blockIdx.x * 16;
    const float4* s4 = (const float4*)(hin + (size_t)row0 * kHC);
    float4* d4 = (float4*)xs;
    d4[t] = s4[t];
    d4[t + 256] = s4[t + 256];
    __syncthreads();

    const int c = t & 127;
    const int half = t >> 7;
    float acc0[8], acc1[8], acc2[8], acc3[8];
#pragma unroll
    for (int r = 0; r < 8; r++) { acc0[r] = 0.f; acc1[r] = 0.f; acc2[r] = 0.f; acc3[r] = 0.f; }
    const float* xbase = xs + (half * 8) * kHC;

    for (int k4 = 0; k4 < kHC; k4 += 4) {
        float4 xv[8];
#pragma unroll
        for (int r = 0; r < 8; r++) xv[r] = *(const float4*)(xbase + r * kHC + k4);
#pragma unroll
        for (int i = 0; i < 4; i++) {
            const int ki = k4 + i;
            const float wq = Wq[ki * kHC + c];
            const float wk = Wk[ki * kHC + c];
            const float wv = Wv[ki * kHC + c];
            const float wsv = Ws[ki * kHC + c];
#pragma unroll
            for (int r = 0; r < 8; r++) {
                const float xvi = ((const float*)&xv[r])[i];
                acc0[r] = fmaf(xvi, wq, acc0[r]);
                acc1[r] = fmaf(xvi, wk, acc1[r]);
                acc2[r] = fmaf(xvi, wv, acc2[r]);
                acc3[r] = fmaf(xvi, wsv, acc3[r]);
            }
        }
    }
    const float bqv = bq[c], bkv = bk[c], bvv = bv[c], bsv = bs[c];
#pragma unroll
    for (int r = 0; r < 8; r++) {
        const size_t o = (size_t)(row0 + half * 8 + r) * kHC + c;
        q[o]  = __float2half(acc0[r] + bqv);
        k[o]  = __float2half(acc1[r] + bkv);
        v[o]  = __float2half(acc2[r] + bvv);
        xr[o] = acc3[r] + bsv;
    }
}

// ---------------- qeW precompute: qeW[d,h,j] = sum_{c in h} q[d,c]*We[j,c] --
// Also qb[d,h] = sum_{c in h} q[d,c]*be[c].  2 nodes per 256-thread block.
__global__ __launch_bounds__(256) void qew_kernel(
    const __half* __restrict__ q16, const float* __restrict__ We,
    const float* __restrict__ be,
    __half* __restrict__ qeW, float* __restrict__ qb)
{
    __shared__ float qs[2 * kHC];
    const int t = threadIdx.x;
    const int n0 = blockIdx.x * 2;
    qs[t] = __half2float(q16[(size_t)n0 * kHC + t]);
    __syncthreads();

    const int nd = t >> 7;          // 0/1
    const int o  = t & 127;
    const int h  = o >> 5;
    const int j  = o & 31;
    const float* qrow = qs + nd * kHC + h * 32;
    const float* wrow = We + j * kHC + h * 32;
    float s = 0.f;
#pragma unroll
    for (int c = 0; c < 32; c++) s = fmaf(qrow[c], wrow[c], s);
    qeW[(size_t)(n0 + nd) * kHC + o] = __float2half(s);
    if (j == 0) {
        const float* brow = be + h * 32;
        float sb = 0.f;
#pragma unroll
        for (int c = 0; c < 32; c++) sb = fmaf(qrow[c], brow[c], sb);
        qb[(n0 + nd) * 4 + h] = sb;
    }
}

// ---------------- CSR build (once per call) ---------------------------------
__global__ __launch_bounds__(256) void hist_kernel(
    const int* __restrict__ dstI, int* __restrict__ deg)
{
    const int e = blockIdx.x * 256 + threadIdx.x;
    if (e < kE) atomicAdd(&deg[dstI[e]], 1);
}

__global__ __launch_bounds__(1024) void scan_kernel(
    const int* __restrict__ deg, int* __restrict__ rowptr, int* __restrict__ cursor)
{
    const int t = threadIdx.x;
    constexpr int CH = (kN + 1023) / 1024;
    const int base = t * CH;
    const int end = base + CH < kN ? base + CH : kN;
    int lsum = 0;
    for (int i = base; i < end; i++) lsum += deg[i];
    __shared__ int sm[1024];
    sm[t] = lsum;
    __syncthreads();
    for (int off = 1; off < 1024; off <<= 1) {
        const int x = (t >= off) ? sm[t - off] : 0;
        __syncthreads();
        sm[t] += x;
        __syncthreads();
    }
    int running = sm[t] - lsum;
    for (int i = base; i < end; i++) {
        rowptr[i] = running;
        cursor[i] = running;
        running += deg[i];
    }
    if (t == 1023) rowptr[kN] = sm[1023];
}

__global__ __launch_bounds__(256) void scatter_kernel(
    const int* __restrict__ srcI, const int* __restrict__ dstI,
    int* __restrict__ cursor, int* __restrict__ esrc, int* __restrict__ eidx,
    int* __restrict__ edst)
{
    const int e = blockIdx.x * 256 + threadIdx.x;
    if (e >= kE) return;
    const int d = dstI[e];
    const int pos = atomicAdd(&cursor[d], 1);
    esrc[pos] = srcI[e];
    eidx[pos] = e;
    edst[pos] = d;
}

// ---------------- Edge pass: aex + ea copy in CSR order ---------------------
// No We work per edge: p = q.k + ea.qeW (folded in one 16-lane reduce).
constexpr int kPreWaves = 32768;  // 8192 blocks x 4 waves
__global__ __launch_bounds__(256) void edge_aex_kernel(
    const __half* __restrict__ q16, const __half* __restrict__ k16,
    const __half* __restrict__ qeW, const float* __restrict__ qb,
    const float* __restrict__ ea,
    const int* __restrict__ esrc, const int* __restrict__ eidx,
    const int* __restrict__ edst,
    float* __restrict__ aex, __half* __restrict__ eacsr)
{
    const int t = threadIdx.x;
    const int wid = blockIdx.x * 4 + (t >> 6);
    const int lane = t & 63;
    const int li = lane & 15;          // index within head group
    const int h  = lane >> 4;

    constexpr int CH = (kE + kPreWaves - 1) / kPreWaves;  // 13
    const int j0 = wid * CH;
    const int j1 = (j0 + CH < kE) ? j0 + CH : kE;
    for (int jj = j0; jj < j1; jj++) {
        const int s   = esrc[jj];
        const int eid = eidx[jj];
        const int d   = edst[jj];
        const float2 kf  = __half22float2(*(const __half2*)&k16[(size_t)s * kHC + 2 * lane]);
        const float2 qf  = __half22float2(*(const __half2*)&q16[(size_t)d * kHC + 2 * lane]);
        const float2 qw  = __half22float2(*(const __half2*)&qeW[(size_t)d * kHC + 2 * lane]);
        const float2 ea2 = *(const float2*)&ea[(size_t)eid * kED + 2 * li];
        float p = qf.x * kf.x + qf.y * kf.y + ea2.x * qw.x + ea2.y * qw.y;
        p += __shfl_xor(p, 1);
        p += __shfl_xor(p, 2);
        p += __shfl_xor(p, 4);
        p += __shfl_xor(p, 8);
        p += qb[d * 4 + h];
        if (li == 0) aex[(size_t)jj * 4 + h] = __expf(p * RSQRT_C);
        if (lane < 16) *(__half2*)&eacsr[(size_t)jj * kED + 2 * lane] =
            __floats2half2_rn(ea2.x, ea2.y);
    }
}

// ---------------- Fused node pass: streams + v-gather + epilogue ------------
__global__ __launch_bounds__(256) void node_kernel(
    const float* __restrict__ aex, const __half* __restrict__ eacsr,
    const __half* __restrict__ v16,
    const int* __restrict__ rowptr, const int* __restrict__ esrc,
    const float* __restrict__ We, const float* __restrict__ be,
    const float* __restrict__ xr, const float* __restrict__ Wb,
    const float* __restrict__ lnw, const float* __restrict__ lnb,
    float* __restrict__ hout)
{
    __shared__ float wes[kED * kHC];   // 16 KB: We staged whole
    const int t = threadIdx.x;
    {
        float4* d4 = (float4*)wes;
        const float4* s4 = (const float4*)We;
#pragma unroll
        for (int i = 0; i < 4; i++) d4[t + 256 * i] = s4[t + 256 * i];
    }
    __syncthreads();

    const int n = blockIdx.x * 4 + (t >> 6);   // grid exact: kN % 4 == 0
    const int lane = t & 63;
    const int c = lane << 1;
    const int li = lane & 15;
    const int h = lane >> 4;

    float acc0 = 0.f, acc1 = 0.f, t0 = 0.f, t1 = 0.f, den = 0.f;
    const int beg = rowptr[n], endp = rowptr[n + 1];
    for (int jj = beg; jj < endp; jj++) {
        const float aexv = aex[(size_t)jj * 4 + h];
        const float2 vf  = __half22float2(*(const __half2*)&v16[(size_t)esrc[jj] * kHC + c]);
        const float2 eaf = __half22float2(*(const __half2*)&eacsr[(size_t)jj * kED + 2 * li]);
        den += aexv;
        acc0 = fmaf(vf.x, aexv, acc0);
        acc1 = fmaf(vf.y, aexv, acc1);
        t0   = fmaf(eaf.x, aexv, t0);
        t1   = fmaf(eaf.y, aexv, t1);
    }
    const float invd = 1.f / (den + 1e-16f);
    float o0 = acc0 * invd;
    float o1 = acc1 * invd;
    const float tn0 = t0 * invd, tn1 = t1 * invd;
    // emb contribution: o[c] += sum_j T[h,j] * We[j,c]  (+ be[c], since sum attn = 1)
    const int gbase = lane & 48;
#pragma unroll
    for (int i = 0; i < 16; i++) {
        const float Ta = __shfl(tn0, gbase | i);
        const float Tb = __shfl(tn1, gbase | i);
        const float2 wa = *(const float2*)&wes[(2 * i) * kHC + c];
        const float2 wb = *(const float2*)&wes[(2 * i + 1) * kHC + c];
        o0 = fmaf(Ta, wa.x, o0); o1 = fmaf(Ta, wa.y, o1);
        o0 = fmaf(Tb, wb.x, o0); o1 = fmaf(Tb, wb.y, o1);
    }
    o0 += be[c];
    o1 += be[c + 1];

    const float2 r = *(const float2*)&xr[(size_t)n * kHC + c];
    float z = o0 * Wb[c] + o1 * Wb[c + 1]
            + r.x * Wb[kHC + c] + r.y * Wb[kHC + c + 1]
            + (o0 - r.x) * Wb[2 * kHC + c] + (o1 - r.y) * Wb[2 * kHC + c + 1];
#pragma unroll
    for (int m = 1; m < 64; m <<= 1) z += __shfl_xor(z, m);
    const float beta = 1.f / (1.f + __expf(-z));

    const float g0 = beta * r.x + (1.f - beta) * o0;
    const float g1 = beta * r.y + (1.f - beta) * o1;

    float sm = g0 + g1;
    float sq = g0 * g0 + g1 * g1;
#pragma unroll
    for (int m = 1; m < 64; m <<= 1) {
        sm += __shfl_xor(sm, m);
        sq += __shfl_xor(sq, m);
    }
    const float mu  = sm * (1.f / kHC);
    const float var = sq * (1.f / kHC) - mu * mu;
    const float inv = rsqrtf(var + EPS_LN);

    float y0 = (g0 - mu) * inv * lnw[c] + lnb[c];
    float y1 = (g1 - mu) * inv * lnw[c + 1] + lnb[c + 1];
    y0 = y0 > 0.f ? y0 : NEG_SLOPE * y0;
    y1 = y1 > 0.f ? y1 : NEG_SLOPE * y1;
    *(float2*)&hout[(size_t)n * kHC + c] = make_float2(y0, y1);
}

extern "C" void kernel_launch(void* const* d_in, const int* in_sizes, int n_in,
                              void* d_out, int out_size, void* d_ws, size_t ws_size,
                              hipStream_t stream)
{
    const float* x   = (const float*)d_in[0];
    const int*   ei  = (const int*)d_in[1];
    const float* ea  = (const float*)d_in[2];
    const float* Wq  = (const float*)d_in[3];
    const float* bq  = (const float*)d_in[4];
    const float* Wk  = (const float*)d_in[5];
    const float* bk  = (const float*)d_in[6];
    const float* Wv  = (const float*)d_in[7];
    const float* bv  = (const float*)d_in[8];
    const float* We  = (const float*)d_in[9];
    const float* be  = (const float*)d_in[10];
    const float* Wsk = (const float*)d_in[11];
    const float* bsk = (const float*)d_in[12];
    const float* Wb  = (const float*)d_in[13];
    const float* lnw = (const float*)d_in[14];
    const float* lnb = (const float*)d_in[15];
    float* out = (float*)d_out;

    const int* srcI = ei;
    const int* dstI = ei + kE;

    // ---- workspace layout (~116 MB) ----
    __half* q16  = (__half*)d_ws;
    __half* k16  = q16 + (size_t)kN * kHC;
    __half* v16  = k16 + (size_t)kN * kHC;
    __half* qeW  = v16 + (size_t)kN * kHC;
    float*  xr   = (float*)(qeW + (size_t)kN * kHC);
    float*  qb   = xr + (size_t)kN * kHC;
    int* deg     = (int*)(qb + (size_t)kN * 4);
    int* rowptr  = deg + kN;
    int* cursor  = rowptr + kN + 1;
    int* esrc    = cursor + kN;
    int* eidx    = esrc + kE;
    int* edst    = eidx + kE;
    float* aex   = (float*)(edst + kE);
    __half* eacs = (__half*)(aex + (size_t)kE * 4);

    // ---- CSR build (edge_index constant across layers) ----
    hipMemsetAsync(deg, 0, (size_t)kN * sizeof(int), stream);
    hist_kernel<<<(kE + 255) / 256, 256, 0, stream>>>(dstI, deg);
    scan_kernel<<<1, 1024, 0, stream>>>(deg, rowptr, cursor);
    scatter_kernel<<<(kE + 255) / 256, 256, 0, stream>>>(srcI, dstI, cursor,
                                                         esrc, eidx, edst);

    const float* hin = x;
    for (int l = 0; l < kL; l++) {
        proj_kernel_h<<<kN / 16, 256, 0, stream>>>(
            hin,
            Wq + (size_t)l * kHC * kHC, bq + (size_t)l * kHC,
            Wk + (size_t)l * kHC * kHC, bk + (size_t)l * kHC,
            Wv + (size_t)l * kHC * kHC, bv + (size_t)l * kHC,
            Wsk + (size_t)l * kHC * kHC, bsk + (size_t)l * kHC,
            q16, k16, v16, xr);
        qew_kernel<<<kN / 2, 256, 0, stream>>>(
            q16, We + (size_t)l * kED * kHC, be + (size_t)l * kHC, qeW, qb);
        edge_aex_kernel<<<kPreWaves / 4, 256, 0, stream>>>(
            q16, k16, qeW, qb, ea, esrc, eidx, edst, aex, eacs);
        node_kernel<<<kN / 4, 256, 0, stream>>>(
            aex, eacs, v16, rowptr, esrc,
            We + (size_t)l * kED * kHC, be + (size_t)l * kHC,
            xr, Wb + (size_t)l * 3 * kHC,
            lnw + (size_t)l * kHC, lnb + (size_t)l * kHC,
            out);
        hin = out;
    }
}

// Round 9
// 691.891 us; speedup vs baseline: 1.4511x; 1.2282x over previous
//
#include <hip/hip_runtime.h>
#include <hip/hip_fp16.h>

constexpr int kN  = 50000;
constexpr int kE  = 400000;
constexpr int kHC = 128;
constexpr int kED = 32;
constexpr int kL  = 2;
#define EPS_LN 1e-5f
#define NEG_SLOPE 0.01f
#define RSQRT_C 0.17677669529663687f  // 1/sqrt(32)

// ---------------- Projection GEMM, fp16 q/k/v outputs + fp32 xr -------------
__global__ __launch_bounds__(256) void proj_kernel_h(
    const float* __restrict__ hin,
    const float* __restrict__ Wq, const float* __restrict__ bq,
    const float* __restrict__ Wk, const float* __restrict__ bk,
    const float* __restrict__ Wv, const float* __restrict__ bv,
    const float* __restrict__ Ws, const float* __restrict__ bs,
    __half* __restrict__ q, __half* __restrict__ k,
    __half* __restrict__ v, float* __restrict__ xr)
{
    __shared__ float xs[16 * kHC];
    const int t = threadIdx.x;
    const int row0 = blockIdx.x * 16;
    const float4* s4 = (const float4*)(hin + (size_t)row0 * kHC);
    float4* d4 = (float4*)xs;
    d4[t] = s4[t];
    d4[t + 256] = s4[t + 256];
    __syncthreads();

    const int c = t & 127;
    const int half = t >> 7;
    float acc0[8], acc1[8], acc2[8], acc3[8];
#pragma unroll
    for (int r = 0; r < 8; r++) { acc0[r] = 0.f; acc1[r] = 0.f; acc2[r] = 0.f; acc3[r] = 0.f; }
    const float* xbase = xs + (half * 8) * kHC;

    for (int k4 = 0; k4 < kHC; k4 += 4) {
        float4 xv[8];
#pragma unroll
        for (int r = 0; r < 8; r++) xv[r] = *(const float4*)(xbase + r * kHC + k4);
#pragma unroll
        for (int i = 0; i < 4; i++) {
            const int ki = k4 + i;
            const float wq = Wq[ki * kHC + c];
            const float wk = Wk[ki * kHC + c];
            const float wv = Wv[ki * kHC + c];
            const float wsv = Ws[ki * kHC + c];
#pragma unroll
            for (int r = 0; r < 8; r++) {
                const float xvi = ((const float*)&xv[r])[i];
                acc0[r] = fmaf(xvi, wq, acc0[r]);
                acc1[r] = fmaf(xvi, wk, acc1[r]);
                acc2[r] = fmaf(xvi, wv, acc2[r]);
                acc3[r] = fmaf(xvi, wsv, acc3[r]);
            }
        }
    }
    const float bqv = bq[c], bkv = bk[c], bvv = bv[c], bsv = bs[c];
#pragma unroll
    for (int r = 0; r < 8; r++) {
        const size_t o = (size_t)(row0 + half * 8 + r) * kHC + c;
        q[o]  = __float2half(acc0[r] + bqv);
        k[o]  = __float2half(acc1[r] + bkv);
        v[o]  = __float2half(acc2[r] + bvv);
        xr[o] = acc3[r] + bsv;
    }
}

// ---------------- qeW: register-blocked, 32 nodes per block -----------------
// Thread owns output o = h*32+j (fixed); We[j, h*32..+31] lives in 32 VGPRs.
constexpr int kQewNPB = 32;
__global__ __launch_bounds__(256) void qew_kernel(
    const __half* __restrict__ q16, const float* __restrict__ We,
    __half* __restrict__ qeW)
{
    const int t = threadIdx.x;
    const int o = t & 127;       // output index = h*32 + j
    const int h = o >> 5;
    const int j = o & 31;
    const int nd = t >> 7;       // two node sub-streams per block

    float we[32];
    const float2* wrow = (const float2*)&We[j * kHC + h * 32];
#pragma unroll
    for (int i = 0; i < 16; i++) {
        const float2 w = wrow[i];
        we[2 * i] = w.x; we[2 * i + 1] = w.y;
    }

    const int n0 = blockIdx.x * kQewNPB;
    for (int i = nd; i < kQewNPB; i += 2) {
        const int n = n0 + i;
        if (n >= kN) break;
        const __half2* qrow = (const __half2*)&q16[(size_t)n * kHC + h * 32];
        float s = 0.f;
#pragma unroll
        for (int ii = 0; ii < 16; ii++) {
            const float2 qf = __half22float2(qrow[ii]);
            s = fmaf(qf.x, we[2 * ii], s);
            s = fmaf(qf.y, we[2 * ii + 1], s);
        }
        qeW[(size_t)n * kHC + o] = __float2half(s);
    }
}

// ---------------- qb[n,h] = sum_{c in h} q[n,c]*be[c] -----------------------
__global__ __launch_bounds__(256) void qb_kernel(
    const __half* __restrict__ q16, const float* __restrict__ be,
    float* __restrict__ qb)
{
    const int g = blockIdx.x * 256 + threadIdx.x;   // n*4 + h
    if (g >= kN * 4) return;
    const int n = g >> 2, h = g & 3;
    const __half2* qrow = (const __half2*)&q16[(size_t)n * kHC + h * 32];
    const float2* brow = (const float2*)&be[h * 32];
    float s = 0.f;
#pragma unroll
    for (int i = 0; i < 16; i++) {
        const float2 qf = __half22float2(qrow[i]);
        const float2 bf = brow[i];
        s = fmaf(qf.x, bf.x, s);
        s = fmaf(qf.y, bf.y, s);
    }
    qb[g] = s;
}

// ---------------- CSR build (once per call) ---------------------------------
__global__ __launch_bounds__(256) void hist_kernel(
    const int* __restrict__ dstI, int* __restrict__ deg)
{
    const int e = blockIdx.x * 256 + threadIdx.x;
    if (e < kE) atomicAdd(&deg[dstI[e]], 1);
}

__global__ __launch_bounds__(1024) void scan_kernel(
    const int* __restrict__ deg, int* __restrict__ rowptr, int* __restrict__ cursor)
{
    const int t = threadIdx.x;
    constexpr int CH = (kN + 1023) / 1024;
    const int base = t * CH;
    const int end = base + CH < kN ? base + CH : kN;
    int lsum = 0;
    for (int i = base; i < end; i++) lsum += deg[i];
    __shared__ int sm[1024];
    sm[t] = lsum;
    __syncthreads();
    for (int off = 1; off < 1024; off <<= 1) {
        const int x = (t >= off) ? sm[t - off] : 0;
        __syncthreads();
        sm[t] += x;
        __syncthreads();
    }
    int running = sm[t] - lsum;
    for (int i = base; i < end; i++) {
        rowptr[i] = running;
        cursor[i] = running;
        running += deg[i];
    }
    if (t == 1023) rowptr[kN] = sm[1023];
}

__global__ __launch_bounds__(256) void scatter_kernel(
    const int* __restrict__ srcI, const int* __restrict__ dstI,
    int* __restrict__ cursor, int* __restrict__ esrc, int* __restrict__ eidx,
    int* __restrict__ edst)
{
    const int e = blockIdx.x * 256 + threadIdx.x;
    if (e >= kE) return;
    const int d = dstI[e];
    const int pos = atomicAdd(&cursor[d], 1);
    esrc[pos] = srcI[e];
    eidx[pos] = e;
    edst[pos] = d;
}

// ---------------- Edge pass: aex + ea copy in CSR order ---------------------
constexpr int kPreWaves = 32768;  // 8192 blocks x 4 waves
__global__ __launch_bounds__(256) void edge_aex_kernel(
    const __half* __restrict__ q16, const __half* __restrict__ k16,
    const __half* __restrict__ qeW, const float* __restrict__ qb,
    const float* __restrict__ ea,
    const int* __restrict__ esrc, const int* __restrict__ eidx,
    const int* __restrict__ edst,
    float* __restrict__ aex, __half* __restrict__ eacsr)
{
    const int t = threadIdx.x;
    const int wid = blockIdx.x * 4 + (t >> 6);
    const int lane = t & 63;
    const int li = lane & 15;          // index within head group
    const int h  = lane >> 4;

    constexpr int CH = (kE + kPreWaves - 1) / kPreWaves;  // 13
    const int j0 = wid * CH;
    const int j1 = (j0 + CH < kE) ? j0 + CH : kE;
    for (int jj = j0; jj < j1; jj++) {
        const int s   = esrc[jj];
        const int eid = eidx[jj];
        const int d   = edst[jj];
        const float2 kf  = __half22float2(*(const __half2*)&k16[(size_t)s * kHC + 2 * lane]);
        const float2 qf  = __half22float2(*(const __half2*)&q16[(size_t)d * kHC + 2 * lane]);
        const float2 qw  = __half22float2(*(const __half2*)&qeW[(size_t)d * kHC + 2 * lane]);
        const float2 ea2 = *(const float2*)&ea[(size_t)eid * kED + 2 * li];
        float p = qf.x * kf.x + qf.y * kf.y + ea2.x * qw.x + ea2.y * qw.y;
        p += __shfl_xor(p, 1);
        p += __shfl_xor(p, 2);
        p += __shfl_xor(p, 4);
        p += __shfl_xor(p, 8);
        p += qb[d * 4 + h];
        if (li == 0) aex[(size_t)jj * 4 + h] = __expf(p * RSQRT_C);
        if (lane < 16) *(__half2*)&eacsr[(size_t)jj * kED + 2 * lane] =
            __floats2half2_rn(ea2.x, ea2.y);
    }
}

// ---------------- Fused node pass: streams + v-gather + epilogue ------------
__global__ __launch_bounds__(256) void node_kernel(
    const float* __restrict__ aex, const __half* __restrict__ eacsr,
    const __half* __restrict__ v16,
    const int* __restrict__ rowptr, const int* __restrict__ esrc,
    const float* __restrict__ We, const float* __restrict__ be,
    const float* __restrict__ xr, const float* __restrict__ Wb,
    const float* __restrict__ lnw, const float* __restrict__ lnb,
    float* __restrict__ hout)
{
    __shared__ float wes[kED * kHC];   // 16 KB: We staged whole
    const int t = threadIdx.x;
    {
        float4* d4 = (float4*)wes;
        const float4* s4 = (const float4*)We;
#pragma unroll
        for (int i = 0; i < 4; i++) d4[t + 256 * i] = s4[t + 256 * i];
    }
    __syncthreads();

    const int n = blockIdx.x * 4 + (t >> 6);   // grid exact: kN % 4 == 0
    const int lane = t & 63;
    const int c = lane << 1;
    const int li = lane & 15;
    const int h = lane >> 4;

    float acc0 = 0.f, acc1 = 0.f, t0 = 0.f, t1 = 0.f, den = 0.f;
    const int beg = rowptr[n], endp = rowptr[n + 1];
    for (int jj = beg; jj < endp; jj++) {
        const float aexv = aex[(size_t)jj * 4 + h];
        const float2 vf  = __half22float2(*(const __half2*)&v16[(size_t)esrc[jj] * kHC + c]);
        const float2 eaf = __half22float2(*(const __half2*)&eacsr[(size_t)jj * kED + 2 * li]);
        den += aexv;
        acc0 = fmaf(vf.x, aexv, acc0);
        acc1 = fmaf(vf.y, aexv, acc1);
        t0   = fmaf(eaf.x, aexv, t0);
        t1   = fmaf(eaf.y, aexv, t1);
    }
    const float invd = 1.f / (den + 1e-16f);
    float o0 = acc0 * invd;
    float o1 = acc1 * invd;
    const float tn0 = t0 * invd, tn1 = t1 * invd;
    // emb contribution: o[c] += sum_j T[h,j] * We[j,c]  (+ be[c], since sum attn = 1)
    const int gbase = lane & 48;
#pragma unroll
    for (int i = 0; i < 16; i++) {
        const float Ta = __shfl(tn0, gbase | i);
        const float Tb = __shfl(tn1, gbase | i);
        const float2 wa = *(const float2*)&wes[(2 * i) * kHC + c];
        const float2 wb = *(const float2*)&wes[(2 * i + 1) * kHC + c];
        o0 = fmaf(Ta, wa.x, o0); o1 = fmaf(Ta, wa.y, o1);
        o0 = fmaf(Tb, wb.x, o0); o1 = fmaf(Tb, wb.y, o1);
    }
    o0 += be[c];
    o1 += be[c + 1];

    const float2 r = *(const float2*)&xr[(size_t)n * kHC + c];
    float z = o0 * Wb[c] + o1 * Wb[c + 1]
            + r.x * Wb[kHC + c] + r.y * Wb[kHC + c + 1]
            + (o0 - r.x) * Wb[2 * kHC + c] + (o1 - r.y) * Wb[2 * kHC + c + 1];
#pragma unroll
    for (int m = 1; m < 64; m <<= 1) z += __shfl_xor(z, m);
    const float beta = 1.f / (1.f + __expf(-z));

    const float g0 = beta * r.x + (1.f - beta) * o0;
    const float g1 = beta * r.y + (1.f - beta) * o1;

    float sm = g0 + g1;
    float sq = g0 * g0 + g1 * g1;
#pragma unroll
    for (int m = 1; m < 64; m <<= 1) {
        sm += __shfl_xor(sm, m);
        sq += __shfl_xor(sq, m);
    }
    const float mu  = sm * (1.f / kHC);
    const float var = sq * (1.f / kHC) - mu * mu;
    const float inv = rsqrtf(var + EPS_LN);

    float y0 = (g0 - mu) * inv * lnw[c] + lnb[c];
    float y1 = (g1 - mu) * inv * lnw[c + 1] + lnb[c + 1];
    y0 = y0 > 0.f ? y0 : NEG_SLOPE * y0;
    y1 = y1 > 0.f ? y1 : NEG_SLOPE * y1;
    *(float2*)&hout[(size_t)n * kHC + c] = make_float2(y0, y1);
}

extern "C" void kernel_launch(void* const* d_in, const int* in_sizes, int n_in,
                              void* d_out, int out_size, void* d_ws, size_t ws_size,
                              hipStream_t stream)
{
    const float* x   = (const float*)d_in[0];
    const int*   ei  = (const int*)d_in[1];
    const float* ea  = (const float*)d_in[2];
    const float* Wq  = (const float*)d_in[3];
    const float* bq  = (const float*)d_in[4];
    const float* Wk  = (const float*)d_in[5];
    const float* bk  = (const float*)d_in[6];
    const float* Wv  = (const float*)d_in[7];
    const float* bv  = (const float*)d_in[8];
    const float* We  = (const float*)d_in[9];
    const float* be  = (const float*)d_in[10];
    const float* Wsk = (const float*)d_in[11];
    const float* bsk = (const float*)d_in[12];
    const float* Wb  = (const float*)d_in[13];
    const float* lnw = (const float*)d_in[14];
    const float* lnb = (const float*)d_in[15];
    float* out = (float*)d_out;

    const int* srcI = ei;
    const int* dstI = ei + kE;

    // ---- workspace layout (~116 MB) ----
    __half* q16  = (__half*)d_ws;
    __half* k16  = q16 + (size_t)kN * kHC;
    __half* v16  = k16 + (size_t)kN * kHC;
    __half* qeW  = v16 + (size_t)kN * kHC;
    float*  xr   = (float*)(qeW + (size_t)kN * kHC);
    float*  qb   = xr + (size_t)kN * kHC;
    int* deg     = (int*)(qb + (size_t)kN * 4);
    int* rowptr  = deg + kN;
    int* cursor  = rowptr + kN + 1;
    int* esrc    = cursor + kN;
    int* eidx    = esrc + kE;
    int* edst    = eidx + kE;
    float* aex   = (float*)(edst + kE);
    __half* eacs = (__half*)(aex + (size_t)kE * 4);

    // ---- CSR build (edge_index constant across layers) ----
    hipMemsetAsync(deg, 0, (size_t)kN * sizeof(int), stream);
    hist_kernel<<<(kE + 255) / 256, 256, 0, stream>>>(dstI, deg);
    scan_kernel<<<1, 1024, 0, stream>>>(deg, rowptr, cursor);
    scatter_kernel<<<(kE + 255) / 256, 256, 0, stream>>>(srcI, dstI, cursor,
                                                         esrc, eidx, edst);

    const float* hin = x;
    for (int l = 0; l < kL; l++) {
        proj_kernel_h<<<kN / 16, 256, 0, stream>>>(
            hin,
            Wq + (size_t)l * kHC * kHC, bq + (size_t)l * kHC,
            Wk + (size_t)l * kHC * kHC, bk + (size_t)l * kHC,
            Wv + (size_t)l * kHC * kHC, bv + (size_t)l * kHC,
            Wsk + (size_t)l * kHC * kHC, bsk + (size_t)l * kHC,
            q16, k16, v16, xr);
        qew_kernel<<<(kN + kQewNPB - 1) / kQewNPB, 256, 0, stream>>>(
            q16, We + (size_t)l * kED * kHC, qeW);
        qb_kernel<<<(kN * 4 + 255) / 256, 256, 0, stream>>>(
            q16, be + (size_t)l * kHC, qb);
        edge_aex_kernel<<<kPreWaves / 4, 256, 0, stream>>>(
            q16, k16, qeW, qb, ea, esrc, eidx, edst, aex, eacs);
        node_kernel<<<kN / 4, 256, 0, stream>>>(
            aex, eacs, v16, rowptr, esrc,
            We + (size_t)l * kED * kHC, be + (size_t)l * kHC,
            xr, Wb + (size_t)l * 3 * kHC,
            lnw + (size_t)l * kHC, lnb + (size_t)l * kHC,
            out);
        hin = out;
    }
}

// Round 10
// 614.402 us; speedup vs baseline: 1.6341x; 1.1261x over previous
//
#include <hip/hip_runtime.h>
#include <hip/hip_fp16.h>

constexpr int kN  = 50000;
constexpr int kE  = 400000;
constexpr int kHC = 128;
constexpr int kED = 32;
constexpr int kL  = 2;
#define EPS_LN 1e-5f
#define NEG_SLOPE 0.01f
#define RSQRT_C 0.17677669529663687f  // 1/sqrt(32)

using half8 = __attribute__((ext_vector_type(8))) _Float16;
using half4 = __attribute__((ext_vector_type(4))) _Float16;
using f32x4 = __attribute__((ext_vector_type(4))) float;

// ---------------- Weight transpose+convert: Wt[mat][n][k] fp16 --------------
__global__ __launch_bounds__(256) void wt_kernel(
    const float* __restrict__ Wq, const float* __restrict__ Wk,
    const float* __restrict__ Wv, const float* __restrict__ Ws,
    _Float16* __restrict__ Wt)
{
    const int g = blockIdx.x * 256 + threadIdx.x;   // 8192 total
    const int n  = g & 127;
    const int kc = (g >> 7) & 15;
    const int mat = g >> 11;
    const float* W = mat == 0 ? Wq : mat == 1 ? Wk : mat == 2 ? Wv : Ws;
    _Float16* dst = Wt + ((size_t)mat * 128 + n) * 128 + kc * 8;
#pragma unroll
    for (int i = 0; i < 8; i++) dst[i] = (_Float16)W[(kc * 8 + i) * kHC + n];
}

// ---------------- MFMA projection: 32 rows/block, wave = matrix -------------
__global__ __launch_bounds__(256) void proj_mfma_kernel(
    const float* __restrict__ hin, const _Float16* __restrict__ Wt,
    const float* __restrict__ bq, const float* __restrict__ bk,
    const float* __restrict__ bv, const float* __restrict__ bs,
    _Float16* __restrict__ q16, _Float16* __restrict__ k16,
    _Float16* __restrict__ v16, float* __restrict__ xr)
{
    __shared__ _Float16 lds_a[4096];          // [mt][ks][lane][8] frag-linear
    __shared__ _Float16 lds_o[3][32 * 132];   // repack staging, stride 132
    const int t = threadIdx.x;
    const int row0 = blockIdx.x * 32;

    // ---- stage A (32x128 fp32 -> fp16 fragments) ----
    {
        const int r  = t >> 3;             // 0..31
        const int k0 = (t & 7) * 16;
        const int row = row0 + r;
        float4 f0, f1, f2, f3;
        if (row < kN) {
            const float4* src = (const float4*)(hin + (size_t)row * kHC + k0);
            f0 = src[0]; f1 = src[1]; f2 = src[2]; f3 = src[3];
        } else {
            f0 = f1 = f2 = f3 = make_float4(0.f, 0.f, 0.f, 0.f);
        }
        const int mt  = r >> 4;
        const int l15 = r & 15;
#pragma unroll
        for (int g = 0; g < 2; g++) {
            const int k  = k0 + g * 8;
            const int ks = k >> 5;
            const int kc = (k >> 3) & 3;
            const float4 a = g ? f2 : f0;
            const float4 b = g ? f3 : f1;
            half8 h;
            h[0] = (_Float16)a.x; h[1] = (_Float16)a.y;
            h[2] = (_Float16)a.z; h[3] = (_Float16)a.w;
            h[4] = (_Float16)b.x; h[5] = (_Float16)b.y;
            h[6] = (_Float16)b.z; h[7] = (_Float16)b.w;
            *(half8*)&lds_a[(((mt * 4 + ks) * 64) + kc * 16 + l15) * 8] = h;
        }
    }
    __syncthreads();

    const int w = t >> 6;        // wave id = matrix id (0:q 1:k 2:v 3:skip)
    const int lane = t & 63;
    const int nrow = lane & 15;
    const int kc4  = (lane >> 4) * 4;

    f32x4 acc[2][8];
    const f32x4 z = {0.f, 0.f, 0.f, 0.f};
#pragma unroll
    for (int mt = 0; mt < 2; mt++)
#pragma unroll
        for (int nt = 0; nt < 8; nt++) acc[mt][nt] = z;

    const _Float16* wtm = Wt + (size_t)w * 128 * 128;
#pragma unroll
    for (int ks = 0; ks < 4; ks++) {
        const half8 a0 = *(const half8*)&lds_a[((0 * 4 + ks) * 64 + lane) * 8];
        const half8 a1 = *(const half8*)&lds_a[((1 * 4 + ks) * 64 + lane) * 8];
#pragma unroll
        for (int nt = 0; nt < 8; nt++) {
            const half8 b = *(const half8*)
                &wtm[(size_t)(nt * 16 + nrow) * 128 + ks * 32 + (lane >> 4) * 8];
            acc[0][nt] = __builtin_amdgcn_mfma_f32_16x16x32_f16(a0, b, acc[0][nt], 0, 0, 0);
            acc[1][nt] = __builtin_amdgcn_mfma_f32_16x16x32_f16(a1, b, acc[1][nt], 0, 0, 0);
        }
    }

    if (w < 3) {
        const float* bias = (w == 0) ? bq : (w == 1) ? bk : bv;
#pragma unroll
        for (int nt = 0; nt < 8; nt++) {
            const float bb = bias[nt * 16 + nrow];
#pragma unroll
            for (int mt = 0; mt < 2; mt++)
#pragma unroll
                for (int r = 0; r < 4; r++)
                    lds_o[w][(mt * 16 + kc4 + r) * 132 + nt * 16 + nrow] =
                        (_Float16)(acc[mt][nt][r] + bb);
        }
    } else {
#pragma unroll
        for (int nt = 0; nt < 8; nt++) {
            const float bb = bs[nt * 16 + nrow];
#pragma unroll
            for (int mt = 0; mt < 2; mt++)
#pragma unroll
                for (int r = 0; r < 4; r++) {
                    const int row = row0 + mt * 16 + kc4 + r;
                    if (row < kN)
                        xr[(size_t)row * kHC + nt * 16 + nrow] = acc[mt][nt][r] + bb;
                }
        }
    }
    __syncthreads();

    // ---- coalesced copy-out of q,k,v ----
    const int rr = t >> 3;
    const int cc = (t & 7) * 16;
    const int grow = row0 + rr;
    if (grow < kN) {
#pragma unroll
        for (int m = 0; m < 3; m++) {
            const _Float16* s = &lds_o[m][rr * 132 + cc];
            _Float16* d = (m == 0 ? q16 : m == 1 ? k16 : v16) + (size_t)grow * kHC + cc;
            half4 v0 = *(const half4*)&s[0];
            half4 v1 = *(const half4*)&s[4];
            half4 v2 = *(const half4*)&s[8];
            half4 v3 = *(const half4*)&s[12];
            *(half4*)&d[0] = v0;  *(half4*)&d[4] = v1;
            *(half4*)&d[8] = v2;  *(half4*)&d[12] = v3;
        }
    }
}

// ---------------- qeW: register-blocked, 32 nodes per block -----------------
constexpr int kQewNPB = 32;
__global__ __launch_bounds__(256) void qew_kernel(
    const __half* __restrict__ q16, const float* __restrict__ We,
    __half* __restrict__ qeW)
{
    const int t = threadIdx.x;
    const int o = t & 127;       // output index = h*32 + j
    const int h = o >> 5;
    const int j = o & 31;
    const int nd = t >> 7;

    float we[32];
    const float2* wrow = (const float2*)&We[j * kHC + h * 32];
#pragma unroll
    for (int i = 0; i < 16; i++) {
        const float2 w = wrow[i];
        we[2 * i] = w.x; we[2 * i + 1] = w.y;
    }

    const int n0 = blockIdx.x * kQewNPB;
    for (int i = nd; i < kQewNPB; i += 2) {
        const int n = n0 + i;
        if (n >= kN) break;
        const __half2* qrow = (const __half2*)&q16[(size_t)n * kHC + h * 32];
        float s = 0.f;
#pragma unroll
        for (int ii = 0; ii < 16; ii++) {
            const float2 qf = __half22float2(qrow[ii]);
            s = fmaf(qf.x, we[2 * ii], s);
            s = fmaf(qf.y, we[2 * ii + 1], s);
        }
        qeW[(size_t)n * kHC + o] = __float2half(s);
    }
}

// ---------------- qb[n,h] = sum_{c in h} q[n,c]*be[c] -----------------------
__global__ __launch_bounds__(256) void qb_kernel(
    const __half* __restrict__ q16, const float* __restrict__ be,
    float* __restrict__ qb)
{
    const int g = blockIdx.x * 256 + threadIdx.x;   // n*4 + h
    if (g >= kN * 4) return;
    const int n = g >> 2, h = g & 3;
    const __half2* qrow = (const __half2*)&q16[(size_t)n * kHC + h * 32];
    const float2* brow = (const float2*)&be[h * 32];
    float s = 0.f;
#pragma unroll
    for (int i = 0; i < 16; i++) {
        const float2 qf = __half22float2(qrow[i]);
        const float2 bf = brow[i];
        s = fmaf(qf.x, bf.x, s);
        s = fmaf(qf.y, bf.y, s);
    }
    qb[g] = s;
}

// ---------------- CSR build (once per call) ---------------------------------
__global__ __launch_bounds__(256) void hist_kernel(
    const int* __restrict__ dstI, int* __restrict__ deg)
{
    const int e = blockIdx.x * 256 + threadIdx.x;
    if (e < kE) atomicAdd(&deg[dstI[e]], 1);
}

__global__ __launch_bounds__(1024) void scan_kernel(
    const int* __restrict__ deg, int* __restrict__ rowptr, int* __restrict__ cursor)
{
    const int t = threadIdx.x;
    constexpr int CH = (kN + 1023) / 1024;
    const int base = t * CH;
    const int end = base + CH < kN ? base + CH : kN;
    int lsum = 0;
    for (int i = base; i < end; i++) lsum += deg[i];
    __shared__ int sm[1024];
    sm[t] = lsum;
    __syncthreads();
    for (int off = 1; off < 1024; off <<= 1) {
        const int x = (t >= off) ? sm[t - off] : 0;
        __syncthreads();
        sm[t] += x;
        __syncthreads();
    }
    int running = sm[t] - lsum;
    for (int i = base; i < end; i++) {
        rowptr[i] = running;
        cursor[i] = running;
        running += deg[i];
    }
    if (t == 1023) rowptr[kN] = sm[1023];
}

__global__ __launch_bounds__(256) void scatter_kernel(
    const int* __restrict__ srcI, const int* __restrict__ dstI,
    int* __restrict__ cursor, int* __restrict__ esrc, int* __restrict__ eidx,
    int* __restrict__ edst)
{
    const int e = blockIdx.x * 256 + threadIdx.x;
    if (e >= kE) return;
    const int d = dstI[e];
    const int pos = atomicAdd(&cursor[d], 1);
    esrc[pos] = srcI[e];
    eidx[pos] = e;
    edst[pos] = d;
}

// ---------------- Edge pass: aex + ea copy in CSR order ---------------------
constexpr int kPreWaves = 32768;  // 8192 blocks x 4 waves
__global__ __launch_bounds__(256) void edge_aex_kernel(
    const __half* __restrict__ q16, const __half* __restrict__ k16,
    const __half* __restrict__ qeW, const float* __restrict__ qb,
    const float* __restrict__ ea,
    const int* __restrict__ esrc, const int* __restrict__ eidx,
    const int* __restrict__ edst,
    float* __restrict__ aex, __half* __restrict__ eacsr)
{
    const int t = threadIdx.x;
    const int wid = blockIdx.x * 4 + (t >> 6);
    const int lane = t & 63;
    const int li = lane & 15;          // index within head group
    const int h  = lane >> 4;

    constexpr int CH = (kE + kPreWaves - 1) / kPreWaves;  // 13
    const int j0 = wid * CH;
    const int j1 = (j0 + CH < kE) ? j0 + CH : kE;
    for (int jj = j0; jj < j1; jj++) {
        const int s   = esrc[jj];
        const int eid = eidx[jj];
        const int d   = edst[jj];
        const float2 kf  = __half22float2(*(const __half2*)&k16[(size_t)s * kHC + 2 * lane]);
        const float2 qf  = __half22float2(*(const __half2*)&q16[(size_t)d * kHC + 2 * lane]);
        const float2 qw  = __half22float2(*(const __half2*)&qeW[(size_t)d * kHC + 2 * lane]);
        const float2 ea2 = *(const float2*)&ea[(size_t)eid * kED + 2 * li];
        float p = qf.x * kf.x + qf.y * kf.y + ea2.x * qw.x + ea2.y * qw.y;
        p += __shfl_xor(p, 1);
        p += __shfl_xor(p, 2);
        p += __shfl_xor(p, 4);
        p += __shfl_xor(p, 8);
        p += qb[d * 4 + h];
        if (li == 0) aex[(size_t)jj * 4 + h] = __expf(p * RSQRT_C);
        if (lane < 16) *(__half2*)&eacsr[(size_t)jj * kED + 2 * lane] =
            __floats2half2_rn(ea2.x, ea2.y);
    }
}

// ---------------- Fused node pass: streams + v-gather + epilogue ------------
__global__ __launch_bounds__(256) void node_kernel(
    const float* __restrict__ aex, const __half* __restrict__ eacsr,
    const __half* __restrict__ v16,
    const int* __restrict__ rowptr, const int* __restrict__ esrc,
    const float* __restrict__ We, const float* __restrict__ be,
    const float* __restrict__ xr, const float* __restrict__ Wb,
    const float* __restrict__ lnw, const float* __restrict__ lnb,
    float* __restrict__ hout)
{
    __shared__ float wes[kED * kHC];   // 16 KB: We staged whole
    const int t = threadIdx.x;
    {
        float4* d4 = (float4*)wes;
        const float4* s4 = (const float4*)We;
#pragma unroll
        for (int i = 0; i < 4; i++) d4[t + 256 * i] = s4[t + 256 * i];
    }
    __syncthreads();

    const int n = blockIdx.x * 4 + (t >> 6);   // grid exact: kN % 4 == 0
    const int lane = t & 63;
    const int c = lane << 1;
    const int li = lane & 15;
    const int h = lane >> 4;

    float acc0 = 0.f, acc1 = 0.f, t0 = 0.f, t1 = 0.f, den = 0.f;
    const int beg = rowptr[n], endp = rowptr[n + 1];
    for (int jj = beg; jj < endp; jj++) {
        const float aexv = aex[(size_t)jj * 4 + h];
        const float2 vf  = __half22float2(*(const __half2*)&v16[(size_t)esrc[jj] * kHC + c]);
        const float2 eaf = __half22float2(*(const __half2*)&eacsr[(size_t)jj * kED + 2 * li]);
        den += aexv;
        acc0 = fmaf(vf.x, aexv, acc0);
        acc1 = fmaf(vf.y, aexv, acc1);
        t0   = fmaf(eaf.x, aexv, t0);
        t1   = fmaf(eaf.y, aexv, t1);
    }
    const float invd = 1.f / (den + 1e-16f);
    float o0 = acc0 * invd;
    float o1 = acc1 * invd;
    const float tn0 = t0 * invd, tn1 = t1 * invd;
    const int gbase = lane & 48;
#pragma unroll
    for (int i = 0; i < 16; i++) {
        const float Ta = __shfl(tn0, gbase | i);
        const float Tb = __shfl(tn1, gbase | i);
        const float2 wa = *(const float2*)&wes[(2 * i) * kHC + c];
        const float2 wb = *(const float2*)&wes[(2 * i + 1) * kHC + c];
        o0 = fmaf(Ta, wa.x, o0); o1 = fmaf(Ta, wa.y, o1);
        o0 = fmaf(Tb, wb.x, o0); o1 = fmaf(Tb, wb.y, o1);
    }
    o0 += be[c];
    o1 += be[c + 1];

    const float2 r = *(const float2*)&xr[(size_t)n * kHC + c];
    float z = o0 * Wb[c] + o1 * Wb[c + 1]
            + r.x * Wb[kHC + c] + r.y * Wb[kHC + c + 1]
            + (o0 - r.x) * Wb[2 * kHC + c] + (o1 - r.y) * Wb[2 * kHC + c + 1];
#pragma unroll
    for (int m = 1; m < 64; m <<= 1) z += __shfl_xor(z, m);
    const float beta = 1.f / (1.f + __expf(-z));

    const float g0 = beta * r.x + (1.f - beta) * o0;
    const float g1 = beta * r.y + (1.f - beta) * o1;

    float sm = g0 + g1;
    float sq = g0 * g0 + g1 * g1;
#pragma unroll
    for (int m = 1; m < 64; m <<= 1) {
        sm += __shfl_xor(sm, m);
        sq += __shfl_xor(sq, m);
    }
    const float mu  = sm * (1.f / kHC);
    const float var = sq * (1.f / kHC) - mu * mu;
    const float inv = rsqrtf(var + EPS_LN);

    float y0 = (g0 - mu) * inv * lnw[c] + lnb[c];
    float y1 = (g1 - mu) * inv * lnw[c + 1] + lnb[c + 1];
    y0 = y0 > 0.f ? y0 : NEG_SLOPE * y0;
    y1 = y1 > 0.f ? y1 : NEG_SLOPE * y1;
    *(float2*)&hout[(size_t)n * kHC + c] = make_float2(y0, y1);
}

extern "C" void kernel_launch(void* const* d_in, const int* in_sizes, int n_in,
                              void* d_out, int out_size, void* d_ws, size_t ws_size,
                              hipStream_t stream)
{
    const float* x   = (const float*)d_in[0];
    const int*   ei  = (const int*)d_in[1];
    const float* ea  = (const float*)d_in[2];
    const float* Wq  = (const float*)d_in[3];
    const float* bq  = (const float*)d_in[4];
    const float* Wk  = (const float*)d_in[5];
    const float* bk  = (const float*)d_in[6];
    const float* Wv  = (const float*)d_in[7];
    const float* bv  = (const float*)d_in[8];
    const float* We  = (const float*)d_in[9];
    const float* be  = (const float*)d_in[10];
    const float* Wsk = (const float*)d_in[11];
    const float* bsk = (const float*)d_in[12];
    const float* Wb  = (const float*)d_in[13];
    const float* lnw = (const float*)d_in[14];
    const float* lnb = (const float*)d_in[15];
    float* out = (float*)d_out;

    const int* srcI = ei;
    const int* dstI = ei + kE;

    // ---- workspace layout (~116 MB) ----
    __half* q16  = (__half*)d_ws;
    __half* k16  = q16 + (size_t)kN * kHC;
    __half* v16  = k16 + (size_t)kN * kHC;
    __half* qeW  = v16 + (size_t)kN * kHC;
    float*  xr   = (float*)(qeW + (size_t)kN * kHC);
    float*  qb   = xr + (size_t)kN * kHC;
    int* deg     = (int*)(qb + (size_t)kN * 4);
    int* rowptr  = deg + kN;
    int* cursor  = rowptr + kN + 1;
    int* esrc    = cursor + kN;
    int* eidx    = esrc + kE;
    int* edst    = eidx + kE;
    float* aex   = (float*)(edst + kE);
    __half* eacs = (__half*)(aex + (size_t)kE * 4);
    _Float16* Wt = (_Float16*)(eacs + (size_t)kE * kED);   // 128 KB

    // ---- CSR build (edge_index constant across layers) ----
    hipMemsetAsync(deg, 0, (size_t)kN * sizeof(int), stream);
    hist_kernel<<<(kE + 255) / 256, 256, 0, stream>>>(dstI, deg);
    scan_kernel<<<1, 1024, 0, stream>>>(deg, rowptr, cursor);
    scatter_kernel<<<(kE + 255) / 256, 256, 0, stream>>>(srcI, dstI, cursor,
                                                         esrc, eidx, edst);

    const float* hin = x;
    for (int l = 0; l < kL; l++) {
        wt_kernel<<<32, 256, 0, stream>>>(
            Wq + (size_t)l * kHC * kHC, Wk + (size_t)l * kHC * kHC,
            Wv + (size_t)l * kHC * kHC, Wsk + (size_t)l * kHC * kHC, Wt);
        proj_mfma_kernel<<<(kN + 31) / 32, 256, 0, stream>>>(
            hin, Wt,
            bq + (size_t)l * kHC, bk + (size_t)l * kHC,
            bv + (size_t)l * kHC, bsk + (size_t)l * kHC,
            (_Float16*)q16, (_Float16*)k16, (_Float16*)v16, xr);
        qew_kernel<<<(kN + kQewNPB - 1) / kQewNPB, 256, 0, stream>>>(
            q16, We + (size_t)l * kED * kHC, qeW);
        qb_kernel<<<(kN * 4 + 255) / 256, 256, 0, stream>>>(
            q16, be + (size_t)l * kHC, qb);
        edge_aex_kernel<<<kPreWaves / 4, 256, 0, stream>>>(
            q16, k16, qeW, qb, ea, esrc, eidx, edst, aex, eacs);
        node_kernel<<<kN / 4, 256, 0, stream>>>(
            aex, eacs, v16, rowptr, esrc,
            We + (size_t)l * kED * kHC, be + (size_t)l * kHC,
            xr, Wb + (size_t)l * 3 * kHC,
            lnw + (size_t)l * kHC, lnb + (size_t)l * kHC,
            out);
        hin = out;
    }
}

// Round 11
// 518.749 us; speedup vs baseline: 1.9354x; 1.1844x over previous
//
#include <hip/hip_runtime.h>
#include <hip/hip_fp16.h>

constexpr int kN  = 50000;
constexpr int kE  = 400000;
constexpr int kHC = 128;
constexpr int kED = 32;
constexpr int kL  = 2;
constexpr int kScanB = (kN + 255) / 256;   // 196
#define EPS_LN 1e-5f
#define NEG_SLOPE 0.01f
#define RSQRT_C 0.17677669529663687f  // 1/sqrt(32)

using half8 = __attribute__((ext_vector_type(8))) _Float16;
using half4 = __attribute__((ext_vector_type(4))) _Float16;
using f32x4 = __attribute__((ext_vector_type(4))) float;

// ---------------- Weight transpose+convert: Wt[mat][n][k] fp16 --------------
__global__ __launch_bounds__(256) void wt_kernel(
    const float* __restrict__ Wq, const float* __restrict__ Wk,
    const float* __restrict__ Wv, const float* __restrict__ Ws,
    _Float16* __restrict__ Wt)
{
    const int g = blockIdx.x * 256 + threadIdx.x;   // 8192 total
    const int n  = g & 127;
    const int kc = (g >> 7) & 15;
    const int mat = g >> 11;
    const float* W = mat == 0 ? Wq : mat == 1 ? Wk : mat == 2 ? Wv : Ws;
    _Float16* dst = Wt + ((size_t)mat * 128 + n) * 128 + kc * 8;
#pragma unroll
    for (int i = 0; i < 8; i++) dst[i] = (_Float16)W[(kc * 8 + i) * kHC + n];
}

// ---------------- MFMA projection: 32 rows/block, wave = matrix -------------
__global__ __launch_bounds__(256) void proj_mfma_kernel(
    const float* __restrict__ hin, const _Float16* __restrict__ Wt,
    const float* __restrict__ bq, const float* __restrict__ bk,
    const float* __restrict__ bv, const float* __restrict__ bs,
    _Float16* __restrict__ q16, _Float16* __restrict__ k16,
    _Float16* __restrict__ v16, float* __restrict__ xr)
{
    __shared__ _Float16 lds_a[4096];          // [mt][ks][lane][8] frag-linear
    __shared__ _Float16 lds_o[3][32 * 132];   // repack staging, stride 132
    const int t = threadIdx.x;
    const int row0 = blockIdx.x * 32;

    // ---- stage A (32x128 fp32 -> fp16 fragments) ----
    {
        const int r  = t >> 3;             // 0..31
        const int k0 = (t & 7) * 16;
        const int row = row0 + r;
        float4 f0, f1, f2, f3;
        if (row < kN) {
            const float4* src = (const float4*)(hin + (size_t)row * kHC + k0);
            f0 = src[0]; f1 = src[1]; f2 = src[2]; f3 = src[3];
        } else {
            f0 = f1 = f2 = f3 = make_float4(0.f, 0.f, 0.f, 0.f);
        }
        const int mt  = r >> 4;
        const int l15 = r & 15;
#pragma unroll
        for (int g = 0; g < 2; g++) {
            const int k  = k0 + g * 8;
            const int ks = k >> 5;
            const int kc = (k >> 3) & 3;
            const float4 a = g ? f2 : f0;
            const float4 b = g ? f3 : f1;
            half8 h;
            h[0] = (_Float16)a.x; h[1] = (_Float16)a.y;
            h[2] = (_Float16)a.z; h[3] = (_Float16)a.w;
            h[4] = (_Float16)b.x; h[5] = (_Float16)b.y;
            h[6] = (_Float16)b.z; h[7] = (_Float16)b.w;
            *(half8*)&lds_a[(((mt * 4 + ks) * 64) + kc * 16 + l15) * 8] = h;
        }
    }
    __syncthreads();

    const int w = t >> 6;        // wave id = matrix id (0:q 1:k 2:v 3:skip)
    const int lane = t & 63;
    const int nrow = lane & 15;
    const int kc4  = (lane >> 4) * 4;

    f32x4 acc[2][8];
    const f32x4 z = {0.f, 0.f, 0.f, 0.f};
#pragma unroll
    for (int mt = 0; mt < 2; mt++)
#pragma unroll
        for (int nt = 0; nt < 8; nt++) acc[mt][nt] = z;

    const _Float16* wtm = Wt + (size_t)w * 128 * 128;
#pragma unroll
    for (int ks = 0; ks < 4; ks++) {
        const half8 a0 = *(const half8*)&lds_a[((0 * 4 + ks) * 64 + lane) * 8];
        const half8 a1 = *(const half8*)&lds_a[((1 * 4 + ks) * 64 + lane) * 8];
#pragma unroll
        for (int nt = 0; nt < 8; nt++) {
            const half8 b = *(const half8*)
                &wtm[(size_t)(nt * 16 + nrow) * 128 + ks * 32 + (lane >> 4) * 8];
            acc[0][nt] = __builtin_amdgcn_mfma_f32_16x16x32_f16(a0, b, acc[0][nt], 0, 0, 0);
            acc[1][nt] = __builtin_amdgcn_mfma_f32_16x16x32_f16(a1, b, acc[1][nt], 0, 0, 0);
        }
    }

    if (w < 3) {
        const float* bias = (w == 0) ? bq : (w == 1) ? bk : bv;
#pragma unroll
        for (int nt = 0; nt < 8; nt++) {
            const float bb = bias[nt * 16 + nrow];
#pragma unroll
            for (int mt = 0; mt < 2; mt++)
#pragma unroll
                for (int r = 0; r < 4; r++)
                    lds_o[w][(mt * 16 + kc4 + r) * 132 + nt * 16 + nrow] =
                        (_Float16)(acc[mt][nt][r] + bb);
        }
    } else {
#pragma unroll
        for (int nt = 0; nt < 8; nt++) {
            const float bb = bs[nt * 16 + nrow];
#pragma unroll
            for (int mt = 0; mt < 2; mt++)
#pragma unroll
                for (int r = 0; r < 4; r++) {
                    const int row = row0 + mt * 16 + kc4 + r;
                    if (row < kN)
                        xr[(size_t)row * kHC + nt * 16 + nrow] = acc[mt][nt][r] + bb;
                }
        }
    }
    __syncthreads();

    // ---- coalesced copy-out of q,k,v ----
    const int rr = t >> 3;
    const int cc = (t & 7) * 16;
    const int grow = row0 + rr;
    if (grow < kN) {
#pragma unroll
        for (int m = 0; m < 3; m++) {
            const _Float16* s = &lds_o[m][rr * 132 + cc];
            _Float16* d = (m == 0 ? q16 : m == 1 ? k16 : v16) + (size_t)grow * kHC + cc;
            half4 v0 = *(const half4*)&s[0];
            half4 v1 = *(const half4*)&s[4];
            half4 v2 = *(const half4*)&s[8];
            half4 v3 = *(const half4*)&s[12];
            *(half4*)&d[0] = v0;  *(half4*)&d[4] = v1;
            *(half4*)&d[8] = v2;  *(half4*)&d[12] = v3;
        }
    }
}

// ---------------- qeW: register-blocked, 32 nodes per block -----------------
constexpr int kQewNPB = 32;
__global__ __launch_bounds__(256) void qew_kernel(
    const __half* __restrict__ q16, const float* __restrict__ We,
    __half* __restrict__ qeW)
{
    const int t = threadIdx.x;
    const int o = t & 127;       // output index = h*32 + j
    const int h = o >> 5;
    const int j = o & 31;
    const int nd = t >> 7;

    float we[32];
    const float2* wrow = (const float2*)&We[j * kHC + h * 32];
#pragma unroll
    for (int i = 0; i < 16; i++) {
        const float2 w = wrow[i];
        we[2 * i] = w.x; we[2 * i + 1] = w.y;
    }

    const int n0 = blockIdx.x * kQewNPB;
    for (int i = nd; i < kQewNPB; i += 2) {
        const int n = n0 + i;
        if (n >= kN) break;
        const __half2* qrow = (const __half2*)&q16[(size_t)n * kHC + h * 32];
        float s = 0.f;
#pragma unroll
        for (int ii = 0; ii < 16; ii++) {
            const float2 qf = __half22float2(qrow[ii]);
            s = fmaf(qf.x, we[2 * ii], s);
            s = fmaf(qf.y, we[2 * ii + 1], s);
        }
        qeW[(size_t)n * kHC + o] = __float2half(s);
    }
}

// ---------------- qb[n,h] = sum_{c in h} q[n,c]*be[c] -----------------------
__global__ __launch_bounds__(256) void qb_kernel(
    const __half* __restrict__ q16, const float* __restrict__ be,
    float* __restrict__ qb)
{
    const int g = blockIdx.x * 256 + threadIdx.x;   // n*4 + h
    if (g >= kN * 4) return;
    const int n = g >> 2, h = g & 3;
    const __half2* qrow = (const __half2*)&q16[(size_t)n * kHC + h * 32];
    const float2* brow = (const float2*)&be[h * 32];
    float s = 0.f;
#pragma unroll
    for (int i = 0; i < 16; i++) {
        const float2 qf = __half22float2(qrow[i]);
        const float2 bf = brow[i];
        s = fmaf(qf.x, bf.x, s);
        s = fmaf(qf.y, bf.y, s);
    }
    qb[g] = s;
}

// ---------------- CSR build (once per call) ---------------------------------
__global__ __launch_bounds__(256) void hist_kernel(
    const int* __restrict__ dstI, int* __restrict__ deg)
{
    const int e = blockIdx.x * 256 + threadIdx.x;
    if (e < kE) atomicAdd(&deg[dstI[e]], 1);
}

// Block-local inclusive scan + per-block sums (196 blocks x 256)
__global__ __launch_bounds__(256) void scanA_kernel(
    const int* __restrict__ deg, int* __restrict__ locInc, int* __restrict__ blockSum)
{
    __shared__ int sm[256];
    const int t = threadIdx.x;
    const int i = blockIdx.x * 256 + t;
    sm[t] = (i < kN) ? deg[i] : 0;
    __syncthreads();
    for (int off = 1; off < 256; off <<= 1) {
        const int x = (t >= off) ? sm[t - off] : 0;
        __syncthreads();
        sm[t] += x;
        __syncthreads();
    }
    if (i < kN) locInc[i] = sm[t];
    if (t == 255) blockSum[blockIdx.x] = sm[255];
}

// Each block reduces preceding blockSums, then writes rowptr/cursor
__global__ __launch_bounds__(256) void scanC_kernel(
    const int* __restrict__ deg, const int* __restrict__ locInc,
    const int* __restrict__ blockSum,
    int* __restrict__ rowptr, int* __restrict__ cursor)
{
    __shared__ int sm[256];
    const int t = threadIdx.x;
    const int b = blockIdx.x;
    sm[t] = (t < b) ? blockSum[t] : 0;   // b <= 195 < 256
    __syncthreads();
    for (int s = 128; s > 0; s >>= 1) {
        if (t < s) sm[t] += sm[t + s];
        __syncthreads();
    }
    const int off = sm[0];
    const int i = b * 256 + t;
    if (i < kN) {
        const int inc = locInc[i];
        const int excl = off + inc - deg[i];
        rowptr[i] = excl;
        cursor[i] = excl;
        if (i == kN - 1) rowptr[kN] = off + inc;
    }
}

__global__ __launch_bounds__(256) void scatter_kernel(
    const int* __restrict__ srcI, const int* __restrict__ dstI,
    int* __restrict__ cursor, int* __restrict__ esrc, int* __restrict__ eidx,
    int* __restrict__ edst)
{
    const int e = blockIdx.x * 256 + threadIdx.x;
    if (e >= kE) return;
    const int d = dstI[e];
    const int pos = atomicAdd(&cursor[d], 1);
    esrc[pos] = srcI[e];
    eidx[pos] = e;
    edst[pos] = d;
}

// ---------------- ea -> CSR-order fp16 copy (once per call) -----------------
__global__ __launch_bounds__(256) void ea_csr_kernel(
    const float* __restrict__ ea, const int* __restrict__ eidx,
    __half* __restrict__ eacsr)
{
    const int g = blockIdx.x * 256 + threadIdx.x;   // kE*16 threads
    if (g >= kE * 16) return;
    const int jj = g >> 4;
    const int li = g & 15;
    const int eid = eidx[jj];
    const float2 ea2 = *(const float2*)&ea[(size_t)eid * kED + 2 * li];
    *(__half2*)&eacsr[(size_t)jj * kED + 2 * li] = __floats2half2_rn(ea2.x, ea2.y);
}

// ---------------- Edge pass: aex in CSR order (all-sequential + gathers) ----
constexpr int kPreWaves = 32768;  // 8192 blocks x 4 waves
__global__ __launch_bounds__(256) void edge_aex_kernel(
    const __half* __restrict__ q16, const __half* __restrict__ k16,
    const __half* __restrict__ qeW, const float* __restrict__ qb,
    const __half* __restrict__ eacsr,
    const int* __restrict__ esrc, const int* __restrict__ edst,
    float* __restrict__ aex)
{
    const int t = threadIdx.x;
    const int wid = blockIdx.x * 4 + (t >> 6);
    const int lane = t & 63;
    const int li = lane & 15;          // index within head group
    const int h  = lane >> 4;

    constexpr int CH = (kE + kPreWaves - 1) / kPreWaves;  // 13
    const int j0 = wid * CH;
    const int j1 = (j0 + CH < kE) ? j0 + CH : kE;
    for (int jj = j0; jj < j1; jj++) {
        const int s = esrc[jj];
        const int d = edst[jj];
        const float2 kf  = __half22float2(*(const __half2*)&k16[(size_t)s * kHC + 2 * lane]);
        const float2 qf  = __half22float2(*(const __half2*)&q16[(size_t)d * kHC + 2 * lane]);
        const float2 qw  = __half22float2(*(const __half2*)&qeW[(size_t)d * kHC + 2 * lane]);
        const float2 eaf = __half22float2(*(const __half2*)&eacsr[(size_t)jj * kED + 2 * li]);
        float p = qf.x * kf.x + qf.y * kf.y + eaf.x * qw.x + eaf.y * qw.y;
        p += __shfl_xor(p, 1);
        p += __shfl_xor(p, 2);
        p += __shfl_xor(p, 4);
        p += __shfl_xor(p, 8);
        p += qb[d * 4 + h];
        if (li == 0) aex[(size_t)jj * 4 + h] = __expf(p * RSQRT_C);
    }
}

// ---------------- Fused node pass: streams + v-gather + epilogue ------------
__global__ __launch_bounds__(256) void node_kernel(
    const float* __restrict__ aex, const __half* __restrict__ eacsr,
    const __half* __restrict__ v16,
    const int* __restrict__ rowptr, const int* __restrict__ esrc,
    const float* __restrict__ We, const float* __restrict__ be,
    const float* __restrict__ xr, const float* __restrict__ Wb,
    const float* __restrict__ lnw, const float* __restrict__ lnb,
    float* __restrict__ hout)
{
    __shared__ float wes[kED * kHC];   // 16 KB: We staged whole
    const int t = threadIdx.x;
    {
        float4* d4 = (float4*)wes;
        const float4* s4 = (const float4*)We;
#pragma unroll
        for (int i = 0; i < 4; i++) d4[t + 256 * i] = s4[t + 256 * i];
    }
    __syncthreads();

    const int n = blockIdx.x * 4 + (t >> 6);   // grid exact: kN % 4 == 0
    const int lane = t & 63;
    const int c = lane << 1;
    const int li = lane & 15;
    const int h = lane >> 4;

    float acc0 = 0.f, acc1 = 0.f, t0 = 0.f, t1 = 0.f, den = 0.f;
    const int beg = rowptr[n], endp = rowptr[n + 1];
    for (int jj = beg; jj < endp; jj++) {
        const float aexv = aex[(size_t)jj * 4 + h];
        const float2 vf  = __half22float2(*(const __half2*)&v16[(size_t)esrc[jj] * kHC + c]);
        const float2 eaf = __half22float2(*(const __half2*)&eacsr[(size_t)jj * kED + 2 * li]);
        den += aexv;
        acc0 = fmaf(vf.x, aexv, acc0);
        acc1 = fmaf(vf.y, aexv, acc1);
        t0   = fmaf(eaf.x, aexv, t0);
        t1   = fmaf(eaf.y, aexv, t1);
    }
    const float invd = 1.f / (den + 1e-16f);
    float o0 = acc0 * invd;
    float o1 = acc1 * invd;
    const float tn0 = t0 * invd, tn1 = t1 * invd;
    const int gbase = lane & 48;
#pragma unroll
    for (int i = 0; i < 16; i++) {
        const float Ta = __shfl(tn0, gbase | i);
        const float Tb = __shfl(tn1, gbase | i);
        const float2 wa = *(const float2*)&wes[(2 * i) * kHC + c];
        const float2 wb = *(const float2*)&wes[(2 * i + 1) * kHC + c];
        o0 = fmaf(Ta, wa.x, o0); o1 = fmaf(Ta, wa.y, o1);
        o0 = fmaf(Tb, wb.x, o0); o1 = fmaf(Tb, wb.y, o1);
    }
    o0 += be[c];
    o1 += be[c + 1];

    const float2 r = *(const float2*)&xr[(size_t)n * kHC + c];
    float z = o0 * Wb[c] + o1 * Wb[c + 1]
            + r.x * Wb[kHC + c] + r.y * Wb[kHC + c + 1]
            + (o0 - r.x) * Wb[2 * kHC + c] + (o1 - r.y) * Wb[2 * kHC + c + 1];
#pragma unroll
    for (int m = 1; m < 64; m <<= 1) z += __shfl_xor(z, m);
    const float beta = 1.f / (1.f + __expf(-z));

    const float g0 = beta * r.x + (1.f - beta) * o0;
    const float g1 = beta * r.y + (1.f - beta) * o1;

    float sm = g0 + g1;
    float sq = g0 * g0 + g1 * g1;
#pragma unroll
    for (int m = 1; m < 64; m <<= 1) {
        sm += __shfl_xor(sm, m);
        sq += __shfl_xor(sq, m);
    }
    const float mu  = sm * (1.f / kHC);
    const float var = sq * (1.f / kHC) - mu * mu;
    const float inv = rsqrtf(var + EPS_LN);

    float y0 = (g0 - mu) * inv * lnw[c] + lnb[c];
    float y1 = (g1 - mu) * inv * lnw[c + 1] + lnb[c + 1];
    y0 = y0 > 0.f ? y0 : NEG_SLOPE * y0;
    y1 = y1 > 0.f ? y1 : NEG_SLOPE * y1;
    *(float2*)&hout[(size_t)n * kHC + c] = make_float2(y0, y1);
}

extern "C" void kernel_launch(void* const* d_in, const int* in_sizes, int n_in,
                              void* d_out, int out_size, void* d_ws, size_t ws_size,
                              hipStream_t stream)
{
    const float* x   = (const float*)d_in[0];
    const int*   ei  = (const int*)d_in[1];
    const float* ea  = (const float*)d_in[2];
    const float* Wq  = (const float*)d_in[3];
    const float* bq  = (const float*)d_in[4];
    const float* Wk  = (const float*)d_in[5];
    const float* bk  = (const float*)d_in[6];
    const float* Wv  = (const float*)d_in[7];
    const float* bv  = (const float*)d_in[8];
    const float* We  = (const float*)d_in[9];
    const float* be  = (const float*)d_in[10];
    const float* Wsk = (const float*)d_in[11];
    const float* bsk = (const float*)d_in[12];
    const float* Wb  = (const float*)d_in[13];
    const float* lnw = (const float*)d_in[14];
    const float* lnb = (const float*)d_in[15];
    float* out = (float*)d_out;

    const int* srcI = ei;
    const int* dstI = ei + kE;

    // ---- workspace layout (~117 MB) ----
    __half* q16  = (__half*)d_ws;
    __half* k16  = q16 + (size_t)kN * kHC;
    __half* v16  = k16 + (size_t)kN * kHC;
    __half* qeW  = v16 + (size_t)kN * kHC;
    float*  xr   = (float*)(qeW + (size_t)kN * kHC);
    float*  qb   = xr + (size_t)kN * kHC;
    int* deg     = (int*)(qb + (size_t)kN * 4);
    int* rowptr  = deg + kN;
    int* cursor  = rowptr + kN + 1;
    int* esrc    = cursor + kN;
    int* eidx    = esrc + kE;
    int* edst    = eidx + kE;
    float* aex   = (float*)(edst + kE);
    __half* eacs = (__half*)(aex + (size_t)kE * 4);
    _Float16* Wt = (_Float16*)(eacs + (size_t)kE * kED);   // 128 KB
    int* locInc  = (int*)(Wt + 4 * 128 * 128);
    int* blockSum = locInc + kN;

    // ---- CSR build (edge_index constant across layers) ----
    hipMemsetAsync(deg, 0, (size_t)kN * sizeof(int), stream);
    hist_kernel<<<(kE + 255) / 256, 256, 0, stream>>>(dstI, deg);
    scanA_kernel<<<kScanB, 256, 0, stream>>>(deg, locInc, blockSum);
    scanC_kernel<<<kScanB, 256, 0, stream>>>(deg, locInc, blockSum, rowptr, cursor);
    scatter_kernel<<<(kE + 255) / 256, 256, 0, stream>>>(srcI, dstI, cursor,
                                                         esrc, eidx, edst);
    ea_csr_kernel<<<(kE * 16 + 255) / 256, 256, 0, stream>>>(ea, eidx, eacs);

    const float* hin = x;
    for (int l = 0; l < kL; l++) {
        wt_kernel<<<32, 256, 0, stream>>>(
            Wq + (size_t)l * kHC * kHC, Wk + (size_t)l * kHC * kHC,
            Wv + (size_t)l * kHC * kHC, Wsk + (size_t)l * kHC * kHC, Wt);
        proj_mfma_kernel<<<(kN + 31) / 32, 256, 0, stream>>>(
            hin, Wt,
            bq + (size_t)l * kHC, bk + (size_t)l * kHC,
            bv + (size_t)l * kHC, bsk + (size_t)l * kHC,
            (_Float16*)q16, (_Float16*)k16, (_Float16*)v16, xr);
        qew_kernel<<<(kN + kQewNPB - 1) / kQewNPB, 256, 0, stream>>>(
            q16, We + (size_t)l * kED * kHC, qeW);
        qb_kernel<<<(kN * 4 + 255) / 256, 256, 0, stream>>>(
            q16, be + (size_t)l * kHC, qb);
        edge_aex_kernel<<<kPreWaves / 4, 256, 0, stream>>>(
            q16, k16, qeW, qb, eacs, esrc, edst, aex);
        node_kernel<<<kN / 4, 256, 0, stream>>>(
            aex, eacs, v16, rowptr, esrc,
            We + (size_t)l * kED * kHC, be + (size_t)l * kHC,
            xr, Wb + (size_t)l * 3 * kHC,
            lnw + (size_t)l * kHC, lnb + (size_t)l * kHC,
            out);
        hin = out;
    }
}

// Round 12
// 488.038 us; speedup vs baseline: 2.0572x; 1.0629x over previous
//
#include <hip/hip_runtime.h>
#include <hip/hip_fp16.h>

constexpr int kN  = 50000;
constexpr int kE  = 400000;
constexpr int kHC = 128;
constexpr int kED = 32;
constexpr int kL  = 2;
constexpr int kScanB = (kN + 255) / 256;   // 196
#define EPS_LN 1e-5f
#define NEG_SLOPE 0.01f
#define RSQRT_C 0.17677669529663687f  // 1/sqrt(32)

using half8 = __attribute__((ext_vector_type(8))) _Float16;
using half4 = __attribute__((ext_vector_type(4))) _Float16;
using f32x4 = __attribute__((ext_vector_type(4))) float;

// ---------------- Weight transpose+convert: Wt[mat][n][k] fp16 --------------
__global__ __launch_bounds__(256) void wt_kernel(
    const float* __restrict__ Wq, const float* __restrict__ Wk,
    const float* __restrict__ Wv, const float* __restrict__ Ws,
    _Float16* __restrict__ Wt)
{
    const int g = blockIdx.x * 256 + threadIdx.x;   // 8192 total
    const int n  = g & 127;
    const int kc = (g >> 7) & 15;
    const int mat = g >> 11;
    const float* W = mat == 0 ? Wq : mat == 1 ? Wk : mat == 2 ? Wv : Ws;
    _Float16* dst = Wt + ((size_t)mat * 128 + n) * 128 + kc * 8;
#pragma unroll
    for (int i = 0; i < 8; i++) dst[i] = (_Float16)W[(kc * 8 + i) * kHC + n];
}

// ---------------- We -> fp16 copy (once per layer) --------------------------
__global__ __launch_bounds__(256) void we16_kernel(
    const float* __restrict__ We, _Float16* __restrict__ We16)
{
    const int g = blockIdx.x * 256 + threadIdx.x;   // 4096
    if (g < kED * kHC) We16[g] = (_Float16)We[g];
}

// ---------------- MFMA projection: 32 rows/block, wave = matrix -------------
template<bool FP16IN>
__global__ __launch_bounds__(256) void proj_mfma_kernel(
    const void* __restrict__ hin_, const _Float16* __restrict__ Wt,
    const float* __restrict__ bq, const float* __restrict__ bk,
    const float* __restrict__ bv, const float* __restrict__ bs,
    _Float16* __restrict__ q16, _Float16* __restrict__ k16,
    _Float16* __restrict__ v16, __half* __restrict__ xr16)
{
    __shared__ _Float16 lds_a[4096];          // [mt][ks][lane][8] frag-linear
    __shared__ _Float16 lds_o[3][32 * 132];   // repack staging, stride 132
    const int t = threadIdx.x;
    const int row0 = blockIdx.x * 32;

    // ---- stage A (32x128 -> fp16 fragments) ----
    {
        const int r  = t >> 3;             // 0..31
        const int k0 = (t & 7) * 16;
        const int row = row0 + r;
        half8 h0 = {0, 0, 0, 0, 0, 0, 0, 0};
        half8 h1 = {0, 0, 0, 0, 0, 0, 0, 0};
        if (row < kN) {
            if constexpr (FP16IN) {
                const _Float16* src = (const _Float16*)hin_ + (size_t)row * kHC + k0;
                h0 = *(const half8*)&src[0];
                h1 = *(const half8*)&src[8];
            } else {
                const float4* src = (const float4*)((const float*)hin_ + (size_t)row * kHC + k0);
                const float4 f0 = src[0], f1 = src[1], f2 = src[2], f3 = src[3];
                h0[0] = (_Float16)f0.x; h0[1] = (_Float16)f0.y;
                h0[2] = (_Float16)f0.z; h0[3] = (_Float16)f0.w;
                h0[4] = (_Float16)f1.x; h0[5] = (_Float16)f1.y;
                h0[6] = (_Float16)f1.z; h0[7] = (_Float16)f1.w;
                h1[0] = (_Float16)f2.x; h1[1] = (_Float16)f2.y;
                h1[2] = (_Float16)f2.z; h1[3] = (_Float16)f2.w;
                h1[4] = (_Float16)f3.x; h1[5] = (_Float16)f3.y;
                h1[6] = (_Float16)f3.z; h1[7] = (_Float16)f3.w;
            }
        }
        const int mt  = r >> 4;
        const int l15 = r & 15;
#pragma unroll
        for (int g = 0; g < 2; g++) {
            const int k  = k0 + g * 8;
            const int ks = k >> 5;
            const int kc = (k >> 3) & 3;
            *(half8*)&lds_a[(((mt * 4 + ks) * 64) + kc * 16 + l15) * 8] = g ? h1 : h0;
        }
    }
    __syncthreads();

    const int w = t >> 6;        // wave id = matrix id (0:q 1:k 2:v 3:skip)
    const int lane = t & 63;
    const int nrow = lane & 15;
    const int kc4  = (lane >> 4) * 4;

    f32x4 acc[2][8];
    const f32x4 z = {0.f, 0.f, 0.f, 0.f};
#pragma unroll
    for (int mt = 0; mt < 2; mt++)
#pragma unroll
        for (int nt = 0; nt < 8; nt++) acc[mt][nt] = z;

    const _Float16* wtm = Wt + (size_t)w * 128 * 128;
#pragma unroll
    for (int ks = 0; ks < 4; ks++) {
        const half8 a0 = *(const half8*)&lds_a[((0 * 4 + ks) * 64 + lane) * 8];
        const half8 a1 = *(const half8*)&lds_a[((1 * 4 + ks) * 64 + lane) * 8];
#pragma unroll
        for (int nt = 0; nt < 8; nt++) {
            const half8 b = *(const half8*)
                &wtm[(size_t)(nt * 16 + nrow) * 128 + ks * 32 + (lane >> 4) * 8];
            acc[0][nt] = __builtin_amdgcn_mfma_f32_16x16x32_f16(a0, b, acc[0][nt], 0, 0, 0);
            acc[1][nt] = __builtin_amdgcn_mfma_f32_16x16x32_f16(a1, b, acc[1][nt], 0, 0, 0);
        }
    }

    if (w < 3) {
        const float* bias = (w == 0) ? bq : (w == 1) ? bk : bv;
#pragma unroll
        for (int nt = 0; nt < 8; nt++) {
            const float bb = bias[nt * 16 + nrow];
#pragma unroll
            for (int mt = 0; mt < 2; mt++)
#pragma unroll
                for (int r = 0; r < 4; r++)
                    lds_o[w][(mt * 16 + kc4 + r) * 132 + nt * 16 + nrow] =
                        (_Float16)(acc[mt][nt][r] + bb);
        }
    } else {
#pragma unroll
        for (int nt = 0; nt < 8; nt++) {
            const float bb = bs[nt * 16 + nrow];
#pragma unroll
            for (int mt = 0; mt < 2; mt++)
#pragma unroll
                for (int r = 0; r < 4; r++) {
                    const int row = row0 + mt * 16 + kc4 + r;
                    if (row < kN)
                        xr16[(size_t)row * kHC + nt * 16 + nrow] =
                            __float2half(acc[mt][nt][r] + bb);
                }
        }
    }
    __syncthreads();

    // ---- coalesced copy-out of q,k,v ----
    const int rr = t >> 3;
    const int cc = (t & 7) * 16;
    const int grow = row0 + rr;
    if (grow < kN) {
#pragma unroll
        for (int m = 0; m < 3; m++) {
            const _Float16* s = &lds_o[m][rr * 132 + cc];
            _Float16* d = (m == 0 ? q16 : m == 1 ? k16 : v16) + (size_t)grow * kHC + cc;
            half4 v0 = *(const half4*)&s[0];
            half4 v1 = *(const half4*)&s[4];
            half4 v2 = *(const half4*)&s[8];
            half4 v3 = *(const half4*)&s[12];
            *(half4*)&d[0] = v0;  *(half4*)&d[4] = v1;
            *(half4*)&d[8] = v2;  *(half4*)&d[12] = v3;
        }
    }
}

// ---------------- qeW: register-blocked, 32 nodes per block -----------------
constexpr int kQewNPB = 32;
__global__ __launch_bounds__(256) void qew_kernel(
    const __half* __restrict__ q16, const float* __restrict__ We,
    __half* __restrict__ qeW)
{
    const int t = threadIdx.x;
    const int o = t & 127;       // output index = h*32 + j
    const int h = o >> 5;
    const int j = o & 31;
    const int nd = t >> 7;

    float we[32];
    const float2* wrow = (const float2*)&We[j * kHC + h * 32];
#pragma unroll
    for (int i = 0; i < 16; i++) {
        const float2 w = wrow[i];
        we[2 * i] = w.x; we[2 * i + 1] = w.y;
    }

    const int n0 = blockIdx.x * kQewNPB;
    for (int i = nd; i < kQewNPB; i += 2) {
        const int n = n0 + i;
        if (n >= kN) break;
        const __half2* qrow = (const __half2*)&q16[(size_t)n * kHC + h * 32];
        float s = 0.f;
#pragma unroll
        for (int ii = 0; ii < 16; ii++) {
            const float2 qf = __half22float2(qrow[ii]);
            s = fmaf(qf.x, we[2 * ii], s);
            s = fmaf(qf.y, we[2 * ii + 1], s);
        }
        qeW[(size_t)n * kHC + o] = __float2half(s);
    }
}

// ---------------- qb[n,h] = sum_{c in h} q[n,c]*be[c] -----------------------
__global__ __launch_bounds__(256) void qb_kernel(
    const __half* __restrict__ q16, const float* __restrict__ be,
    float* __restrict__ qb)
{
    const int g = blockIdx.x * 256 + threadIdx.x;   // n*4 + h
    if (g >= kN * 4) return;
    const int n = g >> 2, h = g & 3;
    const __half2* qrow = (const __half2*)&q16[(size_t)n * kHC + h * 32];
    const float2* brow = (const float2*)&be[h * 32];
    float s = 0.f;
#pragma unroll
    for (int i = 0; i < 16; i++) {
        const float2 qf = __half22float2(qrow[i]);
        const float2 bf = brow[i];
        s = fmaf(qf.x, bf.x, s);
        s = fmaf(qf.y, bf.y, s);
    }
    qb[g] = s;
}

// ---------------- CSR build (once per call) ---------------------------------
__global__ __launch_bounds__(256) void hist_kernel(
    const int* __restrict__ dstI, int* __restrict__ deg)
{
    const int e = blockIdx.x * 256 + threadIdx.x;
    if (e < kE) atomicAdd(&deg[dstI[e]], 1);
}

__global__ __launch_bounds__(256) void scanA_kernel(
    const int* __restrict__ deg, int* __restrict__ locInc, int* __restrict__ blockSum)
{
    __shared__ int sm[256];
    const int t = threadIdx.x;
    const int i = blockIdx.x * 256 + t;
    sm[t] = (i < kN) ? deg[i] : 0;
    __syncthreads();
    for (int off = 1; off < 256; off <<= 1) {
        const int x = (t >= off) ? sm[t - off] : 0;
        __syncthreads();
        sm[t] += x;
        __syncthreads();
    }
    if (i < kN) locInc[i] = sm[t];
    if (t == 255) blockSum[blockIdx.x] = sm[255];
}

__global__ __launch_bounds__(256) void scanC_kernel(
    const int* __restrict__ deg, const int* __restrict__ locInc,
    const int* __restrict__ blockSum,
    int* __restrict__ rowptr, int* __restrict__ cursor)
{
    __shared__ int sm[256];
    const int t = threadIdx.x;
    const int b = blockIdx.x;
    sm[t] = (t < b) ? blockSum[t] : 0;   // b <= 195 < 256
    __syncthreads();
    for (int s = 128; s > 0; s >>= 1) {
        if (t < s) sm[t] += sm[t + s];
        __syncthreads();
    }
    const int off = sm[0];
    const int i = b * 256 + t;
    if (i < kN) {
        const int inc = locInc[i];
        const int excl = off + inc - deg[i];
        rowptr[i] = excl;
        cursor[i] = excl;
        if (i == kN - 1) rowptr[kN] = off + inc;
    }
}

__global__ __launch_bounds__(256) void scatter_kernel(
    const int* __restrict__ srcI, const int* __restrict__ dstI,
    int* __restrict__ cursor, int* __restrict__ esrc, int* __restrict__ eidx,
    int* __restrict__ edst)
{
    const int e = blockIdx.x * 256 + threadIdx.x;
    if (e >= kE) return;
    const int d = dstI[e];
    const int pos = atomicAdd(&cursor[d], 1);
    esrc[pos] = srcI[e];
    eidx[pos] = e;
    edst[pos] = d;
}

// ---------------- ea -> CSR-order fp16 copy (once per call) -----------------
__global__ __launch_bounds__(256) void ea_csr_kernel(
    const float* __restrict__ ea, const int* __restrict__ eidx,
    __half* __restrict__ eacsr)
{
    const int g = blockIdx.x * 256 + threadIdx.x;   // kE*16 threads
    if (g >= kE * 16) return;
    const int jj = g >> 4;
    const int li = g & 15;
    const int eid = eidx[jj];
    const float2 ea2 = *(const float2*)&ea[(size_t)eid * kED + 2 * li];
    *(__half2*)&eacsr[(size_t)jj * kED + 2 * li] = __floats2half2_rn(ea2.x, ea2.y);
}

// ---------------- Edge pass: aex in CSR order -------------------------------
constexpr int kPreWaves = 32768;  // 8192 blocks x 4 waves
__global__ __launch_bounds__(256) void edge_aex_kernel(
    const __half* __restrict__ q16, const __half* __restrict__ k16,
    const __half* __restrict__ qeW, const float* __restrict__ qb,
    const __half* __restrict__ eacsr,
    const int* __restrict__ esrc, const int* __restrict__ edst,
    float* __restrict__ aex)
{
    const int t = threadIdx.x;
    const int wid = blockIdx.x * 4 + (t >> 6);
    const int lane = t & 63;
    const int li = lane & 15;
    const int h  = lane >> 4;

    constexpr int CH = (kE + kPreWaves - 1) / kPreWaves;  // 13
    const int j0 = wid * CH;
    const int j1 = (j0 + CH < kE) ? j0 + CH : kE;
    for (int jj = j0; jj < j1; jj++) {
        const int s = esrc[jj];
        const int d = edst[jj];
        const float2 kf  = __half22float2(*(const __half2*)&k16[(size_t)s * kHC + 2 * lane]);
        const float2 qf  = __half22float2(*(const __half2*)&q16[(size_t)d * kHC + 2 * lane]);
        const float2 qw  = __half22float2(*(const __half2*)&qeW[(size_t)d * kHC + 2 * lane]);
        const float2 eaf = __half22float2(*(const __half2*)&eacsr[(size_t)jj * kED + 2 * li]);
        float p = qf.x * kf.x + qf.y * kf.y + eaf.x * qw.x + eaf.y * qw.y;
        p += __shfl_xor(p, 1);
        p += __shfl_xor(p, 2);
        p += __shfl_xor(p, 4);
        p += __shfl_xor(p, 8);
        p += qb[d * 4 + h];
        if (li == 0) aex[(size_t)jj * 4 + h] = __expf(p * RSQRT_C);
    }
}

// ---------------- Fused node pass: streams + v-gather + epilogue ------------
template<bool LAST>
__global__ __launch_bounds__(256) void node_kernel(
    const float* __restrict__ aex, const __half* __restrict__ eacsr,
    const __half* __restrict__ v16,
    const int* __restrict__ rowptr, const int* __restrict__ esrc,
    const _Float16* __restrict__ We16, const float* __restrict__ be,
    const __half* __restrict__ xr16, const float* __restrict__ Wb,
    const float* __restrict__ lnw, const float* __restrict__ lnb,
    void* __restrict__ hout)
{
    __shared__ __half wes[kED * kHC];   // 8 KB: We fp16 staged whole
    const int t = threadIdx.x;
    {
        float4* d4 = (float4*)wes;
        const float4* s4 = (const float4*)We16;
        d4[t] = s4[t];
        d4[t + 256] = s4[t + 256];
    }
    __syncthreads();

    const int n = blockIdx.x * 4 + (t >> 6);   // grid exact: kN % 4 == 0
    const int lane = t & 63;
    const int c = lane << 1;
    const int li = lane & 15;
    const int h = lane >> 4;

    float acc0 = 0.f, acc1 = 0.f, t0 = 0.f, t1 = 0.f, den = 0.f;
    const int beg = rowptr[n], endp = rowptr[n + 1];
    int jj = beg;
    // 2-edge unroll: two independent load chains in flight
    for (; jj + 2 <= endp; jj += 2) {
        const float a0 = aex[(size_t)jj * 4 + h];
        const float a1 = aex[(size_t)(jj + 1) * 4 + h];
        const int s0 = esrc[jj];
        const int s1 = esrc[jj + 1];
        const float2 v0 = __half22float2(*(const __half2*)&v16[(size_t)s0 * kHC + c]);
        const float2 v1 = __half22float2(*(const __half2*)&v16[(size_t)s1 * kHC + c]);
        const float2 e0 = __half22float2(*(const __half2*)&eacsr[(size_t)jj * kED + 2 * li]);
        const float2 e1 = __half22float2(*(const __half2*)&eacsr[(size_t)(jj + 1) * kED + 2 * li]);
        den += a0 + a1;
        acc0 = fmaf(v0.x, a0, acc0); acc0 = fmaf(v1.x, a1, acc0);
        acc1 = fmaf(v0.y, a0, acc1); acc1 = fmaf(v1.y, a1, acc1);
        t0 = fmaf(e0.x, a0, t0); t0 = fmaf(e1.x, a1, t0);
        t1 = fmaf(e0.y, a0, t1); t1 = fmaf(e1.y, a1, t1);
    }
    if (jj < endp) {
        const float a0 = aex[(size_t)jj * 4 + h];
        const float2 v0 = __half22float2(*(const __half2*)&v16[(size_t)esrc[jj] * kHC + c]);
        const float2 e0 = __half22float2(*(const __half2*)&eacsr[(size_t)jj * kED + 2 * li]);
        den += a0;
        acc0 = fmaf(v0.x, a0, acc0);
        acc1 = fmaf(v0.y, a0, acc1);
        t0 = fmaf(e0.x, a0, t0);
        t1 = fmaf(e0.y, a0, t1);
    }
    const float invd = 1.f / (den + 1e-16f);
    float o0 = acc0 * invd;
    float o1 = acc1 * invd;
    const float tn0 = t0 * invd, tn1 = t1 * invd;
    const int gbase = lane & 48;
#pragma unroll
    for (int i = 0; i < 16; i++) {
        const float Ta = __shfl(tn0, gbase | i);
        const float Tb = __shfl(tn1, gbase | i);
        const float2 wa = __half22float2(*(const __half2*)&wes[(2 * i) * kHC + c]);
        const float2 wb = __half22float2(*(const __half2*)&wes[(2 * i + 1) * kHC + c]);
        o0 = fmaf(Ta, wa.x, o0); o1 = fmaf(Ta, wa.y, o1);
        o0 = fmaf(Tb, wb.x, o0); o1 = fmaf(Tb, wb.y, o1);
    }
    o0 += be[c];
    o1 += be[c + 1];

    const float2 r = __half22float2(*(const __half2*)&xr16[(size_t)n * kHC + c]);
    float z = o0 * Wb[c] + o1 * Wb[c + 1]
            + r.x * Wb[kHC + c] + r.y * Wb[kHC + c + 1]
            + (o0 - r.x) * Wb[2 * kHC + c] + (o1 - r.y) * Wb[2 * kHC + c + 1];
#pragma unroll
    for (int m = 1; m < 64; m <<= 1) z += __shfl_xor(z, m);
    const float beta = 1.f / (1.f + __expf(-z));

    const float g0 = beta * r.x + (1.f - beta) * o0;
    const float g1 = beta * r.y + (1.f - beta) * o1;

    float sm = g0 + g1;
    float sq = g0 * g0 + g1 * g1;
#pragma unroll
    for (int m = 1; m < 64; m <<= 1) {
        sm += __shfl_xor(sm, m);
        sq += __shfl_xor(sq, m);
    }
    const float mu  = sm * (1.f / kHC);
    const float var = sq * (1.f / kHC) - mu * mu;
    const float inv = rsqrtf(var + EPS_LN);

    float y0 = (g0 - mu) * inv * lnw[c] + lnb[c];
    float y1 = (g1 - mu) * inv * lnw[c + 1] + lnb[c + 1];
    y0 = y0 > 0.f ? y0 : NEG_SLOPE * y0;
    y1 = y1 > 0.f ? y1 : NEG_SLOPE * y1;
    if constexpr (LAST) {
        *(float2*)&((float*)hout)[(size_t)n * kHC + c] = make_float2(y0, y1);
    } else {
        *(__half2*)&((__half*)hout)[(size_t)n * kHC + c] = __floats2half2_rn(y0, y1);
    }
}

extern "C" void kernel_launch(void* const* d_in, const int* in_sizes, int n_in,
                              void* d_out, int out_size, void* d_ws, size_t ws_size,
                              hipStream_t stream)
{
    const float* x   = (const float*)d_in[0];
    const int*   ei  = (const int*)d_in[1];
    const float* ea  = (const float*)d_in[2];
    const float* Wq  = (const float*)d_in[3];
    const float* bq  = (const float*)d_in[4];
    const float* Wk  = (const float*)d_in[5];
    const float* bk  = (const float*)d_in[6];
    const float* Wv  = (const float*)d_in[7];
    const float* bv  = (const float*)d_in[8];
    const float* We  = (const float*)d_in[9];
    const float* be  = (const float*)d_in[10];
    const float* Wsk = (const float*)d_in[11];
    const float* bsk = (const float*)d_in[12];
    const float* Wb  = (const float*)d_in[13];
    const float* lnw = (const float*)d_in[14];
    const float* lnb = (const float*)d_in[15];
    float* out = (float*)d_out;

    const int* srcI = ei;
    const int* dstI = ei + kE;

    // ---- workspace layout (~105 MB) ----
    __half* q16  = (__half*)d_ws;
    __half* k16  = q16 + (size_t)kN * kHC;
    __half* v16  = k16 + (size_t)kN * kHC;
    __half* qeW  = v16 + (size_t)kN * kHC;
    __half* xr16 = qeW + (size_t)kN * kHC;
    __half* h16  = xr16 + (size_t)kN * kHC;
    float*  qb   = (float*)(h16 + (size_t)kN * kHC);
    int* deg     = (int*)(qb + (size_t)kN * 4);
    int* rowptr  = deg + kN;
    int* cursor  = rowptr + kN + 1;
    int* esrc    = cursor + kN;
    int* eidx    = esrc + kE;
    int* edst    = eidx + kE;
    float* aex   = (float*)(edst + kE);
    __half* eacs = (__half*)(aex + (size_t)kE * 4);
    _Float16* Wt = (_Float16*)(eacs + (size_t)kE * kED);   // 128 KB
    _Float16* We16 = Wt + 4 * 128 * 128;                   // 8 KB
    int* locInc  = (int*)(We16 + kED * kHC);
    int* blockSum = locInc + kN;

    // ---- CSR build (edge_index constant across layers) ----
    hipMemsetAsync(deg, 0, (size_t)kN * sizeof(int), stream);
    hist_kernel<<<(kE + 255) / 256, 256, 0, stream>>>(dstI, deg);
    scanA_kernel<<<kScanB, 256, 0, stream>>>(deg, locInc, blockSum);
    scanC_kernel<<<kScanB, 256, 0, stream>>>(deg, locInc, blockSum, rowptr, cursor);
    scatter_kernel<<<(kE + 255) / 256, 256, 0, stream>>>(srcI, dstI, cursor,
                                                         esrc, eidx, edst);
    ea_csr_kernel<<<(kE * 16 + 255) / 256, 256, 0, stream>>>(ea, eidx, eacs);

    for (int l = 0; l < kL; l++) {
        wt_kernel<<<32, 256, 0, stream>>>(
            Wq + (size_t)l * kHC * kHC, Wk + (size_t)l * kHC * kHC,
            Wv + (size_t)l * kHC * kHC, Wsk + (size_t)l * kHC * kHC, Wt);
        we16_kernel<<<16, 256, 0, stream>>>(We + (size_t)l * kED * kHC, We16);
        if (l == 0)
            proj_mfma_kernel<false><<<(kN + 31) / 32, 256, 0, stream>>>(
                x, Wt,
                bq + (size_t)l * kHC, bk + (size_t)l * kHC,
                bv + (size_t)l * kHC, bsk + (size_t)l * kHC,
                (_Float16*)q16, (_Float16*)k16, (_Float16*)v16, xr16);
        else
            proj_mfma_kernel<true><<<(kN + 31) / 32, 256, 0, stream>>>(
                h16, Wt,
                bq + (size_t)l * kHC, bk + (size_t)l * kHC,
                bv + (size_t)l * kHC, bsk + (size_t)l * kHC,
                (_Float16*)q16, (_Float16*)k16, (_Float16*)v16, xr16);
        qew_kernel<<<(kN + kQewNPB - 1) / kQewNPB, 256, 0, stream>>>(
            q16, We + (size_t)l * kED * kHC, qeW);
        qb_kernel<<<(kN * 4 + 255) / 256, 256, 0, stream>>>(
            q16, be + (size_t)l * kHC, qb);
        edge_aex_kernel<<<kPreWaves / 4, 256, 0, stream>>>(
            q16, k16, qeW, qb, eacs, esrc, edst, aex);
        if (l == 0)
            node_kernel<false><<<kN / 4, 256, 0, stream>>>(
                aex, eacs, v16, rowptr, esrc,
                We16, be + (size_t)l * kHC,
                xr16, Wb + (size_t)l * 3 * kHC,
                lnw + (size_t)l * kHC, lnb + (size_t)l * kHC,
                h16);
        else
            node_kernel<true><<<kN / 4, 256, 0, stream>>>(
                aex, eacs, v16, rowptr, esrc,
                We16, be + (size_t)l * kHC,
                xr16, Wb + (size_t)l * 3 * kHC,
                lnw + (size_t)l * kHC, lnb + (size_t)l * kHC,
                out);
    }
}

// Round 13
// 415.923 us; speedup vs baseline: 2.4139x; 1.1734x over previous
//
#include <hip/hip_runtime.h>
#include <hip/hip_fp16.h>

constexpr int kN  = 50000;
constexpr int kE  = 400000;
constexpr int kHC = 128;
constexpr int kED = 32;
constexpr int kL  = 2;
constexpr int kScanB = (kN + 255) / 256;   // 196
constexpr int kProjBlocks = 512;           // persistent: 2 per CU
constexpr int kTiles = (kN + 31) / 32;     // 1563
#define EPS_LN 1e-5f
#define NEG_SLOPE 0.01f
#define RSQRT_C 0.17677669529663687f  // 1/sqrt(32)

using half8 = __attribute__((ext_vector_type(8))) _Float16;
using half4 = __attribute__((ext_vector_type(4))) _Float16;
using f32x4 = __attribute__((ext_vector_type(4))) float;

// ---------------- Weight transpose+convert: Wt[mat][n][k] fp16 --------------
__global__ __launch_bounds__(256) void wt_kernel(
    const float* __restrict__ Wq, const float* __restrict__ Wk,
    const float* __restrict__ Wv, const float* __restrict__ Ws,
    _Float16* __restrict__ Wt)
{
    const int g = blockIdx.x * 256 + threadIdx.x;   // 8192 total
    const int n  = g & 127;
    const int kc = (g >> 7) & 15;
    const int mat = g >> 11;
    const float* W = mat == 0 ? Wq : mat == 1 ? Wk : mat == 2 ? Wv : Ws;
    _Float16* dst = Wt + ((size_t)mat * 128 + n) * 128 + kc * 8;
#pragma unroll
    for (int i = 0; i < 8; i++) dst[i] = (_Float16)W[(kc * 8 + i) * kHC + n];
}

// ---------------- We -> fp16 copy (once per layer) --------------------------
__global__ __launch_bounds__(256) void we16_kernel(
    const float* __restrict__ We, _Float16* __restrict__ We16)
{
    const int g = blockIdx.x * 256 + threadIdx.x;   // 4096
    if (g < kED * kHC) We16[g] = (_Float16)We[g];
}

// ---------------- Persistent MFMA projection --------------------------------
// 512 blocks, 4 waves, wave = matrix. B-fragments live in VGPRs (loaded once).
// Grid-stride over 32-row tiles with register-level prefetch of the next tile.
template<bool FP16IN>
__global__ __launch_bounds__(256, 2) void proj_mfma_kernel(
    const void* __restrict__ hin_, const _Float16* __restrict__ Wt,
    const float* __restrict__ bq, const float* __restrict__ bk,
    const float* __restrict__ bv, const float* __restrict__ bs,
    _Float16* __restrict__ q16, _Float16* __restrict__ k16,
    _Float16* __restrict__ v16, _Float16* __restrict__ xr16)
{
    __shared__ _Float16 lds_a[4096];          // [mt][ks][lane][8] frag-linear
    __shared__ _Float16 lds_o[4][32 * 132];   // repack staging, stride 132
    const int t = threadIdx.x;
    const int w = t >> 6;        // wave id = matrix id (0:q 1:k 2:v 3:skip)
    const int lane = t & 63;
    const int nrow = lane & 15;
    const int kc4  = (lane >> 4) * 4;

    // ---- preload B fragments (once) ----
    half8 bf[32];
    {
        const _Float16* wtm = Wt + (size_t)w * 128 * 128;
#pragma unroll
        for (int ks = 0; ks < 4; ks++)
#pragma unroll
            for (int nt = 0; nt < 8; nt++)
                bf[ks * 8 + nt] = *(const half8*)
                    &wtm[(size_t)(nt * 16 + nrow) * 128 + ks * 32 + (lane >> 4) * 8];
    }
    const float bias = (w == 0 ? bq : w == 1 ? bk : w == 2 ? bv : bs)[0 * 0 + 0]
                     * 0.f;  // placeholder to keep type; real bias read below
    (void)bias;

    // stage indexing: thread t handles row r = t>>3 of the tile, 16 cols at (t&7)*16
    const int sr  = t >> 3;
    const int sk0 = (t & 7) * 16;
    const int smt = sr >> 4;
    const int sl15 = sr & 15;

    float4 f[4];
    half8 hh[2];

    auto stage_to_regs = [&](int tile) {
        const int row = tile * 32 + sr;
        if (row < kN) {
            if constexpr (FP16IN) {
                const _Float16* src = (const _Float16*)hin_ + (size_t)row * kHC + sk0;
                hh[0] = *(const half8*)&src[0];
                hh[1] = *(const half8*)&src[8];
            } else {
                const float4* src = (const float4*)((const float*)hin_ + (size_t)row * kHC + sk0);
                f[0] = src[0]; f[1] = src[1]; f[2] = src[2]; f[3] = src[3];
            }
        } else {
            if constexpr (FP16IN) {
                hh[0] = half8{0, 0, 0, 0, 0, 0, 0, 0};
                hh[1] = half8{0, 0, 0, 0, 0, 0, 0, 0};
            } else {
                f[0] = f[1] = f[2] = f[3] = make_float4(0.f, 0.f, 0.f, 0.f);
            }
        }
    };

    auto regs_to_lds = [&]() {
        half8 h0, h1;
        if constexpr (FP16IN) {
            h0 = hh[0]; h1 = hh[1];
        } else {
            h0[0] = (_Float16)f[0].x; h0[1] = (_Float16)f[0].y;
            h0[2] = (_Float16)f[0].z; h0[3] = (_Float16)f[0].w;
            h0[4] = (_Float16)f[1].x; h0[5] = (_Float16)f[1].y;
            h0[6] = (_Float16)f[1].z; h0[7] = (_Float16)f[1].w;
            h1[0] = (_Float16)f[2].x; h1[1] = (_Float16)f[2].y;
            h1[2] = (_Float16)f[2].z; h1[3] = (_Float16)f[2].w;
            h1[4] = (_Float16)f[3].x; h1[5] = (_Float16)f[3].y;
            h1[6] = (_Float16)f[3].z; h1[7] = (_Float16)f[3].w;
        }
#pragma unroll
        for (int g = 0; g < 2; g++) {
            const int k  = sk0 + g * 8;
            const int ks = k >> 5;
            const int kc = (k >> 3) & 3;
            *(half8*)&lds_a[(((smt * 4 + ks) * 64) + kc * 16 + sl15) * 8] = g ? h1 : h0;
        }
    };

    const float* biasp = (w == 0) ? bq : (w == 1) ? bk : (w == 2) ? bv : bs;
    float bb[8];
#pragma unroll
    for (int nt = 0; nt < 8; nt++) bb[nt] = biasp[nt * 16 + nrow];

    int tile = blockIdx.x;
    stage_to_regs(tile);

    for (;;) {
        __syncthreads();            // prior lds_a reads + lds_o copyout done
        regs_to_lds();
        __syncthreads();

        const int next = tile + kProjBlocks;
        const bool more = next < kTiles;
        if (more) stage_to_regs(next);   // loads in flight across compute

        f32x4 acc[2][8];
        const f32x4 z = {0.f, 0.f, 0.f, 0.f};
#pragma unroll
        for (int mt = 0; mt < 2; mt++)
#pragma unroll
            for (int nt = 0; nt < 8; nt++) acc[mt][nt] = z;

#pragma unroll
        for (int ks = 0; ks < 4; ks++) {
            const half8 a0 = *(const half8*)&lds_a[((0 * 4 + ks) * 64 + lane) * 8];
            const half8 a1 = *(const half8*)&lds_a[((1 * 4 + ks) * 64 + lane) * 8];
#pragma unroll
            for (int nt = 0; nt < 8; nt++) {
                acc[0][nt] = __builtin_amdgcn_mfma_f32_16x16x32_f16(a0, bf[ks * 8 + nt], acc[0][nt], 0, 0, 0);
                acc[1][nt] = __builtin_amdgcn_mfma_f32_16x16x32_f16(a1, bf[ks * 8 + nt], acc[1][nt], 0, 0, 0);
            }
        }

        // ---- epilogue: bias + repack all 4 matrices via LDS ----
#pragma unroll
        for (int nt = 0; nt < 8; nt++) {
#pragma unroll
            for (int mt = 0; mt < 2; mt++)
#pragma unroll
                for (int r = 0; r < 4; r++)
                    lds_o[w][(mt * 16 + kc4 + r) * 132 + nt * 16 + nrow] =
                        (_Float16)(acc[mt][nt][r] + bb[nt]);
        }
        __syncthreads();

        // coalesced copy-out of q,k,v,xr
        const int grow = tile * 32 + sr;
        if (grow < kN) {
#pragma unroll
            for (int m = 0; m < 4; m++) {
                const _Float16* s = &lds_o[m][sr * 132 + sk0];
                _Float16* d = (m == 0 ? q16 : m == 1 ? k16 : m == 2 ? v16 : xr16)
                              + (size_t)grow * kHC + sk0;
                half4 v0 = *(const half4*)&s[0];
                half4 v1 = *(const half4*)&s[4];
                half4 v2 = *(const half4*)&s[8];
                half4 v3 = *(const half4*)&s[12];
                *(half4*)&d[0] = v0;  *(half4*)&d[4] = v1;
                *(half4*)&d[8] = v2;  *(half4*)&d[12] = v3;
            }
        }

        if (!more) break;
        tile = next;
    }
}

// ---------------- qeW: register-blocked, 32 nodes per block -----------------
constexpr int kQewNPB = 32;
__global__ __launch_bounds__(256) void qew_kernel(
    const __half* __restrict__ q16, const float* __restrict__ We,
    __half* __restrict__ qeW)
{
    const int t = threadIdx.x;
    const int o = t & 127;       // output index = h*32 + j
    const int h = o >> 5;
    const int j = o & 31;
    const int nd = t >> 7;

    float we[32];
    const float2* wrow = (const float2*)&We[j * kHC + h * 32];
#pragma unroll
    for (int i = 0; i < 16; i++) {
        const float2 w = wrow[i];
        we[2 * i] = w.x; we[2 * i + 1] = w.y;
    }

    const int n0 = blockIdx.x * kQewNPB;
    for (int i = nd; i < kQewNPB; i += 2) {
        const int n = n0 + i;
        if (n >= kN) break;
        const __half2* qrow = (const __half2*)&q16[(size_t)n * kHC + h * 32];
        float s = 0.f;
#pragma unroll
        for (int ii = 0; ii < 16; ii++) {
            const float2 qf = __half22float2(qrow[ii]);
            s = fmaf(qf.x, we[2 * ii], s);
            s = fmaf(qf.y, we[2 * ii + 1], s);
        }
        qeW[(size_t)n * kHC + o] = __float2half(s);
    }
}

// ---------------- qb[n,h] = sum_{c in h} q[n,c]*be[c] -----------------------
__global__ __launch_bounds__(256) void qb_kernel(
    const __half* __restrict__ q16, const float* __restrict__ be,
    float* __restrict__ qb)
{
    const int g = blockIdx.x * 256 + threadIdx.x;   // n*4 + h
    if (g >= kN * 4) return;
    const int n = g >> 2, h = g & 3;
    const __half2* qrow = (const __half2*)&q16[(size_t)n * kHC + h * 32];
    const float2* brow = (const float2*)&be[h * 32];
    float s = 0.f;
#pragma unroll
    for (int i = 0; i < 16; i++) {
        const float2 qf = __half22float2(qrow[i]);
        const float2 bf = brow[i];
        s = fmaf(qf.x, bf.x, s);
        s = fmaf(qf.y, bf.y, s);
    }
    qb[g] = s;
}

// ---------------- CSR build (once per call) ---------------------------------
__global__ __launch_bounds__(256) void hist_kernel(
    const int* __restrict__ dstI, int* __restrict__ deg)
{
    const int e = blockIdx.x * 256 + threadIdx.x;
    if (e < kE) atomicAdd(&deg[dstI[e]], 1);
}

__global__ __launch_bounds__(256) void scanA_kernel(
    const int* __restrict__ deg, int* __restrict__ locInc, int* __restrict__ blockSum)
{
    __shared__ int sm[256];
    const int t = threadIdx.x;
    const int i = blockIdx.x * 256 + t;
    sm[t] = (i < kN) ? deg[i] : 0;
    __syncthreads();
    for (int off = 1; off < 256; off <<= 1) {
        const int x = (t >= off) ? sm[t - off] : 0;
        __syncthreads();
        sm[t] += x;
        __syncthreads();
    }
    if (i < kN) locInc[i] = sm[t];
    if (t == 255) blockSum[blockIdx.x] = sm[255];
}

__global__ __launch_bounds__(256) void scanC_kernel(
    const int* __restrict__ deg, const int* __restrict__ locInc,
    const int* __restrict__ blockSum,
    int* __restrict__ rowptr, int* __restrict__ cursor)
{
    __shared__ int sm[256];
    const int t = threadIdx.x;
    const int b = blockIdx.x;
    sm[t] = (t < b) ? blockSum[t] : 0;   // b <= 195 < 256
    __syncthreads();
    for (int s = 128; s > 0; s >>= 1) {
        if (t < s) sm[t] += sm[t + s];
        __syncthreads();
    }
    const int off = sm[0];
    const int i = b * 256 + t;
    if (i < kN) {
        const int inc = locInc[i];
        const int excl = off + inc - deg[i];
        rowptr[i] = excl;
        cursor[i] = excl;
        if (i == kN - 1) rowptr[kN] = off + inc;
    }
}

__global__ __launch_bounds__(256) void scatter_kernel(
    const int* __restrict__ srcI, const int* __restrict__ dstI,
    int* __restrict__ cursor, int* __restrict__ esrc, int* __restrict__ eidx,
    int* __restrict__ edst)
{
    const int e = blockIdx.x * 256 + threadIdx.x;
    if (e >= kE) return;
    const int d = dstI[e];
    const int pos = atomicAdd(&cursor[d], 1);
    esrc[pos] = srcI[e];
    eidx[pos] = e;
    edst[pos] = d;
}

// ---------------- ea -> CSR-order fp16 copy (once per call) -----------------
__global__ __launch_bounds__(256) void ea_csr_kernel(
    const float* __restrict__ ea, const int* __restrict__ eidx,
    __half* __restrict__ eacsr)
{
    const int g = blockIdx.x * 256 + threadIdx.x;   // kE*16 threads
    if (g >= kE * 16) return;
    const int jj = g >> 4;
    const int li = g & 15;
    const int eid = eidx[jj];
    const float2 ea2 = *(const float2*)&ea[(size_t)eid * kED + 2 * li];
    *(__half2*)&eacsr[(size_t)jj * kED + 2 * li] = __floats2half2_rn(ea2.x, ea2.y);
}

// ---------------- Edge pass: aex in CSR order -------------------------------
constexpr int kPreWaves = 32768;  // 8192 blocks x 4 waves
__global__ __launch_bounds__(256) void edge_aex_kernel(
    const __half* __restrict__ q16, const __half* __restrict__ k16,
    const __half* __restrict__ qeW, const float* __restrict__ qb,
    const __half* __restrict__ eacsr,
    const int* __restrict__ esrc, const int* __restrict__ edst,
    float* __restrict__ aex)
{
    const int t = threadIdx.x;
    const int wid = blockIdx.x * 4 + (t >> 6);
    const int lane = t & 63;
    const int li = lane & 15;
    const int h  = lane >> 4;

    constexpr int CH = (kE + kPreWaves - 1) / kPreWaves;  // 13
    const int j0 = wid * CH;
    const int j1 = (j0 + CH < kE) ? j0 + CH : kE;
    for (int jj = j0; jj < j1; jj++) {
        const int s = esrc[jj];
        const int d = edst[jj];
        const float2 kf  = __half22float2(*(const __half2*)&k16[(size_t)s * kHC + 2 * lane]);
        const float2 qf  = __half22float2(*(const __half2*)&q16[(size_t)d * kHC + 2 * lane]);
        const float2 qw  = __half22float2(*(const __half2*)&qeW[(size_t)d * kHC + 2 * lane]);
        const float2 eaf = __half22float2(*(const __half2*)&eacsr[(size_t)jj * kED + 2 * li]);
        float p = qf.x * kf.x + qf.y * kf.y + eaf.x * qw.x + eaf.y * qw.y;
        p += __shfl_xor(p, 1);
        p += __shfl_xor(p, 2);
        p += __shfl_xor(p, 4);
        p += __shfl_xor(p, 8);
        p += qb[d * 4 + h];
        if (li == 0) aex[(size_t)jj * 4 + h] = __expf(p * RSQRT_C);
    }
}

// ---------------- Fused node pass: streams + v-gather + epilogue ------------
template<bool LAST>
__global__ __launch_bounds__(256) void node_kernel(
    const float* __restrict__ aex, const __half* __restrict__ eacsr,
    const __half* __restrict__ v16,
    const int* __restrict__ rowptr, const int* __restrict__ esrc,
    const _Float16* __restrict__ We16, const float* __restrict__ be,
    const __half* __restrict__ xr16, const float* __restrict__ Wb,
    const float* __restrict__ lnw, const float* __restrict__ lnb,
    void* __restrict__ hout)
{
    __shared__ __half wes[kED * kHC];   // 8 KB: We fp16 staged whole
    const int t = threadIdx.x;
    {
        float4* d4 = (float4*)wes;
        const float4* s4 = (const float4*)We16;
        d4[t] = s4[t];
        d4[t + 256] = s4[t + 256];
    }
    __syncthreads();

    const int n = blockIdx.x * 4 + (t >> 6);   // grid exact: kN % 4 == 0
    const int lane = t & 63;
    const int c = lane << 1;
    const int li = lane & 15;
    const int h = lane >> 4;

    float acc0 = 0.f, acc1 = 0.f, t0 = 0.f, t1 = 0.f, den = 0.f;
    const int beg = rowptr[n], endp = rowptr[n + 1];
    int jj = beg;
    for (; jj + 2 <= endp; jj += 2) {
        const float a0 = aex[(size_t)jj * 4 + h];
        const float a1 = aex[(size_t)(jj + 1) * 4 + h];
        const int s0 = esrc[jj];
        const int s1 = esrc[jj + 1];
        const float2 v0 = __half22float2(*(const __half2*)&v16[(size_t)s0 * kHC + c]);
        const float2 v1 = __half22float2(*(const __half2*)&v16[(size_t)s1 * kHC + c]);
        const float2 e0 = __half22float2(*(const __half2*)&eacsr[(size_t)jj * kED + 2 * li]);
        const float2 e1 = __half22float2(*(const __half2*)&eacsr[(size_t)(jj + 1) * kED + 2 * li]);
        den += a0 + a1;
        acc0 = fmaf(v0.x, a0, acc0); acc0 = fmaf(v1.x, a1, acc0);
        acc1 = fmaf(v0.y, a0, acc1); acc1 = fmaf(v1.y, a1, acc1);
        t0 = fmaf(e0.x, a0, t0); t0 = fmaf(e1.x, a1, t0);
        t1 = fmaf(e0.y, a0, t1); t1 = fmaf(e1.y, a1, t1);
    }
    if (jj < endp) {
        const float a0 = aex[(size_t)jj * 4 + h];
        const float2 v0 = __half22float2(*(const __half2*)&v16[(size_t)esrc[jj] * kHC + c]);
        const float2 e0 = __half22float2(*(const __half2*)&eacsr[(size_t)jj * kED + 2 * li]);
        den += a0;
        acc0 = fmaf(v0.x, a0, acc0);
        acc1 = fmaf(v0.y, a0, acc1);
        t0 = fmaf(e0.x, a0, t0);
        t1 = fmaf(e0.y, a0, t1);
    }
    const float invd = 1.f / (den + 1e-16f);
    float o0 = acc0 * invd;
    float o1 = acc1 * invd;
    const float tn0 = t0 * invd, tn1 = t1 * invd;
    const int gbase = lane & 48;
#pragma unroll
    for (int i = 0; i < 16; i++) {
        const float Ta = __shfl(tn0, gbase | i);
        const float Tb = __shfl(tn1, gbase | i);
        const float2 wa = __half22float2(*(const __half2*)&wes[(2 * i) * kHC + c]);
        const float2 wb = __half22float2(*(const __half2*)&wes[(2 * i + 1) * kHC + c]);
        o0 = fmaf(Ta, wa.x, o0); o1 = fmaf(Ta, wa.y, o1);
        o0 = fmaf(Tb, wb.x, o0); o1 = fmaf(Tb, wb.y, o1);
    }
    o0 += be[c];
    o1 += be[c + 1];

    const float2 r = __half22float2(*(const __half2*)&xr16[(size_t)n * kHC + c]);
    float z = o0 * Wb[c] + o1 * Wb[c + 1]
            + r.x * Wb[kHC + c] + r.y * Wb[kHC + c + 1]
            + (o0 - r.x) * Wb[2 * kHC + c] + (o1 - r.y) * Wb[2 * kHC + c + 1];
#pragma unroll
    for (int m = 1; m < 64; m <<= 1) z += __shfl_xor(z, m);
    const float beta = 1.f / (1.f + __expf(-z));

    const float g0 = beta * r.x + (1.f - beta) * o0;
    const float g1 = beta * r.y + (1.f - beta) * o1;

    float sm = g0 + g1;
    float sq = g0 * g0 + g1 * g1;
#pragma unroll
    for (int m = 1; m < 64; m <<= 1) {
        sm += __shfl_xor(sm, m);
        sq += __shfl_xor(sq, m);
    }
    const float mu  = sm * (1.f / kHC);
    const float var = sq * (1.f / kHC) - mu * mu;
    const float inv = rsqrtf(var + EPS_LN);

    float y0 = (g0 - mu) * inv * lnw[c] + lnb[c];
    float y1 = (g1 - mu) * inv * lnw[c + 1] + lnb[c + 1];
    y0 = y0 > 0.f ? y0 : NEG_SLOPE * y0;
    y1 = y1 > 0.f ? y1 : NEG_SLOPE * y1;
    if constexpr (LAST) {
        *(float2*)&((float*)hout)[(size_t)n * kHC + c] = make_float2(y0, y1);
    } else {
        *(__half2*)&((__half*)hout)[(size_t)n * kHC + c] = __floats2half2_rn(y0, y1);
    }
}

extern "C" void kernel_launch(void* const* d_in, const int* in_sizes, int n_in,
                              void* d_out, int out_size, void* d_ws, size_t ws_size,
                              hipStream_t stream)
{
    const float* x   = (const float*)d_in[0];
    const int*   ei  = (const int*)d_in[1];
    const float* ea  = (const float*)d_in[2];
    const float* Wq  = (const float*)d_in[3];
    const float* bq  = (const float*)d_in[4];
    const float* Wk  = (const float*)d_in[5];
    const float* bk  = (const float*)d_in[6];
    const float* Wv  = (const float*)d_in[7];
    const float* bv  = (const float*)d_in[8];
    const float* We  = (const float*)d_in[9];
    const float* be  = (const float*)d_in[10];
    const float* Wsk = (const float*)d_in[11];
    const float* bsk = (const float*)d_in[12];
    const float* Wb  = (const float*)d_in[13];
    const float* lnw = (const float*)d_in[14];
    const float* lnb = (const float*)d_in[15];
    float* out = (float*)d_out;

    const int* srcI = ei;
    const int* dstI = ei + kE;

    // ---- workspace layout (~105 MB) ----
    __half* q16  = (__half*)d_ws;
    __half* k16  = q16 + (size_t)kN * kHC;
    __half* v16  = k16 + (size_t)kN * kHC;
    __half* qeW  = v16 + (size_t)kN * kHC;
    __half* xr16 = qeW + (size_t)kN * kHC;
    __half* h16  = xr16 + (size_t)kN * kHC;
    float*  qb   = (float*)(h16 + (size_t)kN * kHC);
    int* deg     = (int*)(qb + (size_t)kN * 4);
    int* rowptr  = deg + kN;
    int* cursor  = rowptr + kN + 1;
    int* esrc    = cursor + kN;
    int* eidx    = esrc + kE;
    int* edst    = eidx + kE;
    float* aex   = (float*)(edst + kE);
    __half* eacs = (__half*)(aex + (size_t)kE * 4);
    _Float16* Wt = (_Float16*)(eacs + (size_t)kE * kED);   // 128 KB
    _Float16* We16 = Wt + 4 * 128 * 128;                   // 8 KB
    int* locInc  = (int*)(We16 + kED * kHC);
    int* blockSum = locInc + kN;

    // ---- CSR build (edge_index constant across layers) ----
    hipMemsetAsync(deg, 0, (size_t)kN * sizeof(int), stream);
    hist_kernel<<<(kE + 255) / 256, 256, 0, stream>>>(dstI, deg);
    scanA_kernel<<<kScanB, 256, 0, stream>>>(deg, locInc, blockSum);
    scanC_kernel<<<kScanB, 256, 0, stream>>>(deg, locInc, blockSum, rowptr, cursor);
    scatter_kernel<<<(kE + 255) / 256, 256, 0, stream>>>(srcI, dstI, cursor,
                                                         esrc, eidx, edst);
    ea_csr_kernel<<<(kE * 16 + 255) / 256, 256, 0, stream>>>(ea, eidx, eacs);

    for (int l = 0; l < kL; l++) {
        wt_kernel<<<32, 256, 0, stream>>>(
            Wq + (size_t)l * kHC * kHC, Wk + (size_t)l * kHC * kHC,
            Wv + (size_t)l * kHC * kHC, Wsk + (size_t)l * kHC * kHC, Wt);
        we16_kernel<<<16, 256, 0, stream>>>(We + (size_t)l * kHC * kED, We16);
        if (l == 0)
            proj_mfma_kernel<false><<<kProjBlocks, 256, 0, stream>>>(
                x, Wt,
                bq + (size_t)l * kHC, bk + (size_t)l * kHC,
                bv + (size_t)l * kHC, bsk + (size_t)l * kHC,
                (_Float16*)q16, (_Float16*)k16, (_Float16*)v16, (_Float16*)xr16);
        else
            proj_mfma_kernel<true><<<kProjBlocks, 256, 0, stream>>>(
                h16, Wt,
                bq + (size_t)l * kHC, bk + (size_t)l * kHC,
                bv + (size_t)l * kHC, bsk + (size_t)l * kHC,
                (_Float16*)q16, (_Float16*)k16, (_Float16*)v16, (_Float16*)xr16);
        qew_kernel<<<(kN + kQewNPB - 1) / kQewNPB, 256, 0, stream>>>(
            q16, We + (size_t)l * kED * kHC, qeW);
        qb_kernel<<<(kN * 4 + 255) / 256, 256, 0, stream>>>(
            q16, be + (size_t)l * kHC, qb);
        edge_aex_kernel<<<kPreWaves / 4, 256, 0, stream>>>(
            q16, k16, qeW, qb, eacs, esrc, edst, aex);
        if (l == 0)
            node_kernel<false><<<kN / 4, 256, 0, stream>>>(
                aex, eacs, v16, rowptr, esrc,
                We16, be + (size_t)l * kHC,
                xr16, Wb + (size_t)l * 3 * kHC,
                lnw + (size_t)l * kHC, lnb + (size_t)l * kHC,
                h16);
        else
            node_kernel<true><<<kN / 4, 256, 0, stream>>>(
                aex, eacs, v16, rowptr, esrc,
                We16, be + (size_t)l * kHC,
                xr16, Wb + (size_t)l * 3 * kHC,
                lnw + (size_t)l * kHC, lnb + (size_t)l * kHC,
                out);
    }
}

// Round 14
// 311.609 us; speedup vs baseline: 3.2219x; 1.3348x over previous
//
#include <hip/hip_runtime.h>
#include <hip/hip_fp16.h>

constexpr int kN  = 50000;
constexpr int kE  = 400000;
constexpr int kHC = 128;
constexpr int kED = 32;
constexpr int kL  = 2;
constexpr int kScanB = (kN + 255) / 256;   // 196
constexpr int kProjBlocks = 512;           // persistent: 2 per CU
constexpr int kTiles = (kN + 31) / 32;     // 1563
#define EPS_LN 1e-5f
#define NEG_SLOPE 0.01f
#define RSQRT_C 0.17677669529663687f  // 1/sqrt(32)

using half8 = __attribute__((ext_vector_type(8))) _Float16;
using half4 = __attribute__((ext_vector_type(4))) _Float16;
using f32x4 = __attribute__((ext_vector_type(4))) float;

// ---------------- Weight transpose+convert: Wt[mat][n][k] fp16 --------------
__global__ __launch_bounds__(256) void wt_kernel(
    const float* __restrict__ Wq, const float* __restrict__ Wk,
    const float* __restrict__ Wv, const float* __restrict__ Ws,
    _Float16* __restrict__ Wt)
{
    const int g = blockIdx.x * 256 + threadIdx.x;   // 8192 total
    const int n  = g & 127;
    const int kc = (g >> 7) & 15;
    const int mat = g >> 11;
    const float* W = mat == 0 ? Wq : mat == 1 ? Wk : mat == 2 ? Wv : Ws;
    _Float16* dst = Wt + ((size_t)mat * 128 + n) * 128 + kc * 8;
#pragma unroll
    for (int i = 0; i < 8; i++) dst[i] = (_Float16)W[(kc * 8 + i) * kHC + n];
}

// ---------------- We -> fp16 copy (once per layer) --------------------------
__global__ __launch_bounds__(256) void we16_kernel(
    const float* __restrict__ We, _Float16* __restrict__ We16)
{
    const int g = blockIdx.x * 256 + threadIdx.x;   // 4096
    if (g < kED * kHC) We16[g] = (_Float16)We[g];
}

// ---------------- Persistent MFMA projection --------------------------------
// outputs: q16 [n][128], kv16 [n][256] (k|v interleaved), xr16 [n][128]
template<bool FP16IN>
__global__ __launch_bounds__(256, 2) void proj_mfma_kernel(
    const void* __restrict__ hin_, const _Float16* __restrict__ Wt,
    const float* __restrict__ bq, const float* __restrict__ bk,
    const float* __restrict__ bv, const float* __restrict__ bs,
    _Float16* __restrict__ q16, _Float16* __restrict__ kv16,
    _Float16* __restrict__ xr16)
{
    __shared__ _Float16 lds_a[4096];          // [mt][ks][lane][8] frag-linear
    __shared__ _Float16 lds_o[4][32 * 132];   // repack staging, stride 132
    const int t = threadIdx.x;
    const int w = t >> 6;        // wave id = matrix id (0:q 1:k 2:v 3:skip)
    const int lane = t & 63;
    const int nrow = lane & 15;
    const int kc4  = (lane >> 4) * 4;

    // ---- preload B fragments (once) ----
    half8 bf[32];
    {
        const _Float16* wtm = Wt + (size_t)w * 128 * 128;
#pragma unroll
        for (int ks = 0; ks < 4; ks++)
#pragma unroll
            for (int nt = 0; nt < 8; nt++)
                bf[ks * 8 + nt] = *(const half8*)
                    &wtm[(size_t)(nt * 16 + nrow) * 128 + ks * 32 + (lane >> 4) * 8];
    }

    const int sr  = t >> 3;
    const int sk0 = (t & 7) * 16;
    const int smt = sr >> 4;
    const int sl15 = sr & 15;

    float4 f[4];
    half8 hh[2];

    auto stage_to_regs = [&](int tile) {
        const int row = tile * 32 + sr;
        if (row < kN) {
            if constexpr (FP16IN) {
                const _Float16* src = (const _Float16*)hin_ + (size_t)row * kHC + sk0;
                hh[0] = *(const half8*)&src[0];
                hh[1] = *(const half8*)&src[8];
            } else {
                const float4* src = (const float4*)((const float*)hin_ + (size_t)row * kHC + sk0);
                f[0] = src[0]; f[1] = src[1]; f[2] = src[2]; f[3] = src[3];
            }
        } else {
            if constexpr (FP16IN) {
                hh[0] = half8{0, 0, 0, 0, 0, 0, 0, 0};
                hh[1] = half8{0, 0, 0, 0, 0, 0, 0, 0};
            } else {
                f[0] = f[1] = f[2] = f[3] = make_float4(0.f, 0.f, 0.f, 0.f);
            }
        }
    };

    auto regs_to_lds = [&]() {
        half8 h0, h1;
        if constexpr (FP16IN) {
            h0 = hh[0]; h1 = hh[1];
        } else {
            h0[0] = (_Float16)f[0].x; h0[1] = (_Float16)f[0].y;
            h0[2] = (_Float16)f[0].z; h0[3] = (_Float16)f[0].w;
            h0[4] = (_Float16)f[1].x; h0[5] = (_Float16)f[1].y;
            h0[6] = (_Float16)f[1].z; h0[7] = (_Float16)f[1].w;
            h1[0] = (_Float16)f[2].x; h1[1] = (_Float16)f[2].y;
            h1[2] = (_Float16)f[2].z; h1[3] = (_Float16)f[2].w;
            h1[4] = (_Float16)f[3].x; h1[5] = (_Float16)f[3].y;
            h1[6] = (_Float16)f[3].z; h1[7] = (_Float16)f[3].w;
        }
#pragma unroll
        for (int g = 0; g < 2; g++) {
            const int k  = sk0 + g * 8;
            const int ks = k >> 5;
            const int kc = (k >> 3) & 3;
            *(half8*)&lds_a[(((smt * 4 + ks) * 64) + kc * 16 + sl15) * 8] = g ? h1 : h0;
        }
    };

    const float* biasp = (w == 0) ? bq : (w == 1) ? bk : (w == 2) ? bv : bs;
    float bb[8];
#pragma unroll
    for (int nt = 0; nt < 8; nt++) bb[nt] = biasp[nt * 16 + nrow];

    int tile = blockIdx.x;
    stage_to_regs(tile);

    for (;;) {
        __syncthreads();
        regs_to_lds();
        __syncthreads();

        const int next = tile + kProjBlocks;
        const bool more = next < kTiles;
        if (more) stage_to_regs(next);

        f32x4 acc[2][8];
        const f32x4 z = {0.f, 0.f, 0.f, 0.f};
#pragma unroll
        for (int mt = 0; mt < 2; mt++)
#pragma unroll
            for (int nt = 0; nt < 8; nt++) acc[mt][nt] = z;

#pragma unroll
        for (int ks = 0; ks < 4; ks++) {
            const half8 a0 = *(const half8*)&lds_a[((0 * 4 + ks) * 64 + lane) * 8];
            const half8 a1 = *(const half8*)&lds_a[((1 * 4 + ks) * 64 + lane) * 8];
#pragma unroll
            for (int nt = 0; nt < 8; nt++) {
                acc[0][nt] = __builtin_amdgcn_mfma_f32_16x16x32_f16(a0, bf[ks * 8 + nt], acc[0][nt], 0, 0, 0);
                acc[1][nt] = __builtin_amdgcn_mfma_f32_16x16x32_f16(a1, bf[ks * 8 + nt], acc[1][nt], 0, 0, 0);
            }
        }

#pragma unroll
        for (int nt = 0; nt < 8; nt++) {
#pragma unroll
            for (int mt = 0; mt < 2; mt++)
#pragma unroll
                for (int r = 0; r < 4; r++)
                    lds_o[w][(mt * 16 + kc4 + r) * 132 + nt * 16 + nrow] =
                        (_Float16)(acc[mt][nt][r] + bb[nt]);
        }
        __syncthreads();

        // coalesced copy-out: q, k->kv[0:128), v->kv[128:256), xr
        const int grow = tile * 32 + sr;
        if (grow < kN) {
#pragma unroll
            for (int m = 0; m < 4; m++) {
                const _Float16* s = &lds_o[m][sr * 132 + sk0];
                _Float16* d;
                if (m == 0)      d = q16  + (size_t)grow * kHC + sk0;
                else if (m == 1) d = kv16 + (size_t)grow * 256 + sk0;
                else if (m == 2) d = kv16 + (size_t)grow * 256 + 128 + sk0;
                else             d = xr16 + (size_t)grow * kHC + sk0;
                half4 v0 = *(const half4*)&s[0];
                half4 v1 = *(const half4*)&s[4];
                half4 v2 = *(const half4*)&s[8];
                half4 v3 = *(const half4*)&s[12];
                *(half4*)&d[0] = v0;  *(half4*)&d[4] = v1;
                *(half4*)&d[8] = v2;  *(half4*)&d[12] = v3;
            }
        }

        if (!more) break;
        tile = next;
    }
}

// ---------------- qeW: register-blocked, 32 nodes per block -----------------
constexpr int kQewNPB = 32;
__global__ __launch_bounds__(256) void qew_kernel(
    const __half* __restrict__ q16, const float* __restrict__ We,
    __half* __restrict__ qeW)
{
    const int t = threadIdx.x;
    const int o = t & 127;       // output index = h*32 + j
    const int h = o >> 5;
    const int j = o & 31;
    const int nd = t >> 7;

    float we[32];
    const float2* wrow = (const float2*)&We[j * kHC + h * 32];
#pragma unroll
    for (int i = 0; i < 16; i++) {
        const float2 w = wrow[i];
        we[2 * i] = w.x; we[2 * i + 1] = w.y;
    }

    const int n0 = blockIdx.x * kQewNPB;
    for (int i = nd; i < kQewNPB; i += 2) {
        const int n = n0 + i;
        if (n >= kN) break;
        const __half2* qrow = (const __half2*)&q16[(size_t)n * kHC + h * 32];
        float s = 0.f;
#pragma unroll
        for (int ii = 0; ii < 16; ii++) {
            const float2 qf = __half22float2(qrow[ii]);
            s = fmaf(qf.x, we[2 * ii], s);
            s = fmaf(qf.y, we[2 * ii + 1], s);
        }
        qeW[(size_t)n * kHC + o] = __float2half(s);
    }
}

// ---------------- qb[n,h] = sum_{c in h} q[n,c]*be[c] -----------------------
__global__ __launch_bounds__(256) void qb_kernel(
    const __half* __restrict__ q16, const float* __restrict__ be,
    float* __restrict__ qb)
{
    const int g = blockIdx.x * 256 + threadIdx.x;   // n*4 + h
    if (g >= kN * 4) return;
    const int n = g >> 2, h = g & 3;
    const __half2* qrow = (const __half2*)&q16[(size_t)n * kHC + h * 32];
    const float2* brow = (const float2*)&be[h * 32];
    float s = 0.f;
#pragma unroll
    for (int i = 0; i < 16; i++) {
        const float2 qf = __half22float2(qrow[i]);
        const float2 bf = brow[i];
        s = fmaf(qf.x, bf.x, s);
        s = fmaf(qf.y, bf.y, s);
    }
    qb[g] = s;
}

// ---------------- CSR build (once per call) ---------------------------------
__global__ __launch_bounds__(256) void hist_kernel(
    const int* __restrict__ dstI, int* __restrict__ deg)
{
    const int e = blockIdx.x * 256 + threadIdx.x;
    if (e < kE) atomicAdd(&deg[dstI[e]], 1);
}

__global__ __launch_bounds__(256) void scanA_kernel(
    const int* __restrict__ deg, int* __restrict__ locInc, int* __restrict__ blockSum)
{
    __shared__ int sm[256];
    const int t = threadIdx.x;
    const int i = blockIdx.x * 256 + t;
    sm[t] = (i < kN) ? deg[i] : 0;
    __syncthreads();
    for (int off = 1; off < 256; off <<= 1) {
        const int x = (t >= off) ? sm[t - off] : 0;
        __syncthreads();
        sm[t] += x;
        __syncthreads();
    }
    if (i < kN) locInc[i] = sm[t];
    if (t == 255) blockSum[blockIdx.x] = sm[255];
}

__global__ __launch_bounds__(256) void scanC_kernel(
    const int* __restrict__ deg, const int* __restrict__ locInc,
    const int* __restrict__ blockSum,
    int* __restrict__ rowptr, int* __restrict__ cursor)
{
    __shared__ int sm[256];
    const int t = threadIdx.x;
    const int b = blockIdx.x;
    sm[t] = (t < b) ? blockSum[t] : 0;   // b <= 195 < 256
    __syncthreads();
    for (int s = 128; s > 0; s >>= 1) {
        if (t < s) sm[t] += sm[t + s];
        __syncthreads();
    }
    const int off = sm[0];
    const int i = b * 256 + t;
    if (i < kN) {
        const int inc = locInc[i];
        const int excl = off + inc - deg[i];
        rowptr[i] = excl;
        cursor[i] = excl;
        if (i == kN - 1) rowptr[kN] = off + inc;
    }
}

__global__ __launch_bounds__(256) void scatter_kernel(
    const int* __restrict__ srcI, const int* __restrict__ dstI,
    int* __restrict__ cursor, int* __restrict__ esrc, int* __restrict__ eidx)
{
    const int e = blockIdx.x * 256 + threadIdx.x;
    if (e >= kE) return;
    const int d = dstI[e];
    const int pos = atomicAdd(&cursor[d], 1);
    esrc[pos] = srcI[e];
    eidx[pos] = e;
}

// ---------------- ea -> CSR-order fp16 copy (once per call) -----------------
__global__ __launch_bounds__(256) void ea_csr_kernel(
    const float* __restrict__ ea, const int* __restrict__ eidx,
    __half* __restrict__ eacsr)
{
    const int g = blockIdx.x * 256 + threadIdx.x;   // kE*16 threads
    if (g >= kE * 16) return;
    const int jj = g >> 4;
    const int li = g & 15;
    const int eid = eidx[jj];
    const float2 ea2 = *(const float2*)&ea[(size_t)eid * kED + 2 * li];
    *(__half2*)&eacsr[(size_t)jj * kED + 2 * li] = __floats2half2_rn(ea2.x, ea2.y);
}

// ---------------- Fused node pass: logits + softmax + agg + epilogue --------
template<bool LAST>
__global__ __launch_bounds__(256) void node_kernel(
    const __half* __restrict__ q16, const __half* __restrict__ qeW,
    const float* __restrict__ qb, const __half* __restrict__ eacsr,
    const __half* __restrict__ kv16,
    const int* __restrict__ rowptr, const int* __restrict__ esrc,
    const _Float16* __restrict__ We16, const float* __restrict__ be,
    const __half* __restrict__ xr16, const float* __restrict__ Wb,
    const float* __restrict__ lnw, const float* __restrict__ lnb,
    void* __restrict__ hout)
{
    __shared__ __half wes[kED * kHC];   // 8 KB: We fp16 staged whole
    const int t = threadIdx.x;
    {
        float4* d4 = (float4*)wes;
        const float4* s4 = (const float4*)We16;
        d4[t] = s4[t];
        d4[t + 256] = s4[t + 256];
    }
    __syncthreads();

    const int n = blockIdx.x * 4 + (t >> 6);   // grid exact: kN % 4 == 0
    const int lane = t & 63;
    const int c = lane << 1;
    const int li = lane & 15;
    const int h = lane >> 4;

    // loop-invariant per node
    const float2 qf = __half22float2(*(const __half2*)&q16[(size_t)n * kHC + c]);
    const float2 qw = __half22float2(*(const __half2*)&qeW[(size_t)n * kHC + c]);
    const float qbv = qb[n * 4 + h];
    const __half2* kv2 = (const __half2*)kv16;

    float acc0 = 0.f, acc1 = 0.f, t0 = 0.f, t1 = 0.f, den = 0.f;
    const int beg = rowptr[n], endp = rowptr[n + 1];
    int jj = beg;
    for (; jj + 2 <= endp; jj += 2) {
        const int s0 = esrc[jj];
        const int s1 = esrc[jj + 1];
        const float2 k0 = __half22float2(kv2[(size_t)s0 * 128 + lane]);
        const float2 k1 = __half22float2(kv2[(size_t)s1 * 128 + lane]);
        const float2 v0 = __half22float2(kv2[(size_t)s0 * 128 + 64 + lane]);
        const float2 v1 = __half22float2(kv2[(size_t)s1 * 128 + 64 + lane]);
        const float2 e0 = __half22float2(*(const __half2*)&eacsr[(size_t)jj * kED + 2 * li]);
        const float2 e1 = __half22float2(*(const __half2*)&eacsr[(size_t)(jj + 1) * kED + 2 * li]);
        float p0 = qf.x * k0.x + qf.y * k0.y + qw.x * e0.x + qw.y * e0.y;
        float p1 = qf.x * k1.x + qf.y * k1.y + qw.x * e1.x + qw.y * e1.y;
        p0 += __shfl_xor(p0, 1);  p1 += __shfl_xor(p1, 1);
        p0 += __shfl_xor(p0, 2);  p1 += __shfl_xor(p1, 2);
        p0 += __shfl_xor(p0, 4);  p1 += __shfl_xor(p1, 4);
        p0 += __shfl_xor(p0, 8);  p1 += __shfl_xor(p1, 8);
        const float a0 = __expf((p0 + qbv) * RSQRT_C);
        const float a1 = __expf((p1 + qbv) * RSQRT_C);
        den += a0 + a1;
        acc0 = fmaf(v0.x, a0, acc0); acc0 = fmaf(v1.x, a1, acc0);
        acc1 = fmaf(v0.y, a0, acc1); acc1 = fmaf(v1.y, a1, acc1);
        t0 = fmaf(e0.x, a0, t0); t0 = fmaf(e1.x, a1, t0);
        t1 = fmaf(e0.y, a0, t1); t1 = fmaf(e1.y, a1, t1);
    }
    if (jj < endp) {
        const int s0 = esrc[jj];
        const float2 k0 = __half22float2(kv2[(size_t)s0 * 128 + lane]);
        const float2 v0 = __half22float2(kv2[(size_t)s0 * 128 + 64 + lane]);
        const float2 e0 = __half22float2(*(const __half2*)&eacsr[(size_t)jj * kED + 2 * li]);
        float p0 = qf.x * k0.x + qf.y * k0.y + qw.x * e0.x + qw.y * e0.y;
        p0 += __shfl_xor(p0, 1);
        p0 += __shfl_xor(p0, 2);
        p0 += __shfl_xor(p0, 4);
        p0 += __shfl_xor(p0, 8);
        const float a0 = __expf((p0 + qbv) * RSQRT_C);
        den += a0;
        acc0 = fmaf(v0.x, a0, acc0);
        acc1 = fmaf(v0.y, a0, acc1);
        t0 = fmaf(e0.x, a0, t0);
        t1 = fmaf(e0.y, a0, t1);
    }
    const float invd = 1.f / (den + 1e-16f);
    float o0 = acc0 * invd;
    float o1 = acc1 * invd;
    const float tn0 = t0 * invd, tn1 = t1 * invd;
    const int gbase = lane & 48;
#pragma unroll
    for (int i = 0; i < 16; i++) {
        const float Ta = __shfl(tn0, gbase | i);
        const float Tb = __shfl(tn1, gbase | i);
        const float2 wa = __half22float2(*(const __half2*)&wes[(2 * i) * kHC + c]);
        const float2 wb = __half22float2(*(const __half2*)&wes[(2 * i + 1) * kHC + c]);
        o0 = fmaf(Ta, wa.x, o0); o1 = fmaf(Ta, wa.y, o1);
        o0 = fmaf(Tb, wb.x, o0); o1 = fmaf(Tb, wb.y, o1);
    }
    o0 += be[c];
    o1 += be[c + 1];

    const float2 r = __half22float2(*(const __half2*)&xr16[(size_t)n * kHC + c]);
    float z = o0 * Wb[c] + o1 * Wb[c + 1]
            + r.x * Wb[kHC + c] + r.y * Wb[kHC + c + 1]
            + (o0 - r.x) * Wb[2 * kHC + c] + (o1 - r.y) * Wb[2 * kHC + c + 1];
#pragma unroll
    for (int m = 1; m < 64; m <<= 1) z += __shfl_xor(z, m);
    const float beta = 1.f / (1.f + __expf(-z));

    const float g0 = beta * r.x + (1.f - beta) * o0;
    const float g1 = beta * r.y + (1.f - beta) * o1;

    float sm = g0 + g1;
    float sq = g0 * g0 + g1 * g1;
#pragma unroll
    for (int m = 1; m < 64; m <<= 1) {
        sm += __shfl_xor(sm, m);
        sq += __shfl_xor(sq, m);
    }
    const float mu  = sm * (1.f / kHC);
    const float var = sq * (1.f / kHC) - mu * mu;
    const float inv = rsqrtf(var + EPS_LN);

    float y0 = (g0 - mu) * inv * lnw[c] + lnb[c];
    float y1 = (g1 - mu) * inv * lnw[c + 1] + lnb[c + 1];
    y0 = y0 > 0.f ? y0 : NEG_SLOPE * y0;
    y1 = y1 > 0.f ? y1 : NEG_SLOPE * y1;
    if constexpr (LAST) {
        *(float2*)&((float*)hout)[(size_t)n * kHC + c] = make_float2(y0, y1);
    } else {
        *(__half2*)&((__half*)hout)[(size_t)n * kHC + c] = __floats2half2_rn(y0, y1);
    }
}

extern "C" void kernel_launch(void* const* d_in, const int* in_sizes, int n_in,
                              void* d_out, int out_size, void* d_ws, size_t ws_size,
                              hipStream_t stream)
{
    const float* x   = (const float*)d_in[0];
    const int*   ei  = (const int*)d_in[1];
    const float* ea  = (const float*)d_in[2];
    const float* Wq  = (const float*)d_in[3];
    const float* bq  = (const float*)d_in[4];
    const float* Wk  = (const float*)d_in[5];
    const float* bk  = (const float*)d_in[6];
    const float* Wv  = (const float*)d_in[7];
    const float* bv  = (const float*)d_in[8];
    const float* We  = (const float*)d_in[9];
    const float* be  = (const float*)d_in[10];
    const float* Wsk = (const float*)d_in[11];
    const float* bsk = (const float*)d_in[12];
    const float* Wb  = (const float*)d_in[13];
    const float* lnw = (const float*)d_in[14];
    const float* lnb = (const float*)d_in[15];
    float* out = (float*)d_out;

    const int* srcI = ei;
    const int* dstI = ei + kE;

    // ---- workspace layout (~100 MB) ----
    __half* q16  = (__half*)d_ws;
    __half* kv16 = q16 + (size_t)kN * kHC;              // [n][256] k|v
    __half* qeW  = kv16 + (size_t)kN * 256;
    __half* xr16 = qeW + (size_t)kN * kHC;
    __half* h16  = xr16 + (size_t)kN * kHC;
    float*  qb   = (float*)(h16 + (size_t)kN * kHC);
    int* deg     = (int*)(qb + (size_t)kN * 4);
    int* rowptr  = deg + kN;
    int* cursor  = rowptr + kN + 1;
    int* esrc    = cursor + kN;
    int* eidx    = esrc + kE;
    __half* eacs = (__half*)(eidx + kE);
    _Float16* Wt = (_Float16*)(eacs + (size_t)kE * kED);   // 128 KB
    _Float16* We16 = Wt + 4 * 128 * 128;                   // 8 KB
    int* locInc  = (int*)(We16 + kED * kHC);
    int* blockSum = locInc + kN;

    // ---- CSR build (edge_index constant across layers) ----
    hipMemsetAsync(deg, 0, (size_t)kN * sizeof(int), stream);
    hist_kernel<<<(kE + 255) / 256, 256, 0, stream>>>(dstI, deg);
    scanA_kernel<<<kScanB, 256, 0, stream>>>(deg, locInc, blockSum);
    scanC_kernel<<<kScanB, 256, 0, stream>>>(deg, locInc, blockSum, rowptr, cursor);
    scatter_kernel<<<(kE + 255) / 256, 256, 0, stream>>>(srcI, dstI, cursor, esrc, eidx);
    ea_csr_kernel<<<(kE * 16 + 255) / 256, 256, 0, stream>>>(ea, eidx, eacs);

    for (int l = 0; l < kL; l++) {
        wt_kernel<<<32, 256, 0, stream>>>(
            Wq + (size_t)l * kHC * kHC, Wk + (size_t)l * kHC * kHC,
            Wv + (size_t)l * kHC * kHC, Wsk + (size_t)l * kHC * kHC, Wt);
        we16_kernel<<<16, 256, 0, stream>>>(We + (size_t)l * kHC * kED, We16);
        if (l == 0)
            proj_mfma_kernel<false><<<kProjBlocks, 256, 0, stream>>>(
                x, Wt,
                bq + (size_t)l * kHC, bk + (size_t)l * kHC,
                bv + (size_t)l * kHC, bsk + (size_t)l * kHC,
                (_Float16*)q16, (_Float16*)kv16, (_Float16*)xr16);
        else
            proj_mfma_kernel<true><<<kProjBlocks, 256, 0, stream>>>(
                h16, Wt,
                bq + (size_t)l * kHC, bk + (size_t)l * kHC,
                bv + (size_t)l * kHC, bsk + (size_t)l * kHC,
                (_Float16*)q16, (_Float16*)kv16, (_Float16*)xr16);
        qew_kernel<<<(kN + kQewNPB - 1) / kQewNPB, 256, 0, stream>>>(
            q16, We + (size_t)l * kED * kHC, qeW);
        qb_kernel<<<(kN * 4 + 255) / 256, 256, 0, stream>>>(
            q16, be + (size_t)l * kHC, qb);
        if (l == 0)
            node_kernel<false><<<kN / 4, 256, 0, stream>>>(
                q16, qeW, qb, eacs, kv16, rowptr, esrc,
                We16, be + (size_t)l * kHC,
                xr16, Wb + (size_t)l * 3 * kHC,
                lnw + (size_t)l * kHC, lnb + (size_t)l * kHC,
                h16);
        else
            node_kernel<true><<<kN / 4, 256, 0, stream>>>(
                q16, qeW, qb, eacs, kv16, rowptr, esrc,
                We16, be + (size_t)l * kHC,
                xr16, Wb + (size_t)l * 3 * kHC,
                lnw + (size_t)l * kHC, lnb + (size_t)l * kHC,
                out);
    }
}